// Round 7
// baseline (249.511 us; speedup 1.0000x reference)
//
#include <hip/hip_runtime.h>

typedef unsigned short u16;
typedef unsigned int   u32;
typedef u16  u16x2 __attribute__((ext_vector_type(2)));
typedef u16  u16x4 __attribute__((ext_vector_type(4)));
typedef u16  u16x8 __attribute__((ext_vector_type(8)));
typedef short s8v  __attribute__((ext_vector_type(8)));   // 8 bf16, MFMA A/B frag (K=32 shapes)
typedef float f4v  __attribute__((ext_vector_type(4)));   // MFMA C/D frag
typedef u32  u32x2 __attribute__((ext_vector_type(2)));
typedef u32  u32x4 __attribute__((ext_vector_type(4)));

#define L_SEQ 2048
#define B_SZ  4
#define E_DIM 512
#define H_CNT 8
#define HD    64
#define HID   2048
#define M_ROWS (L_SEQ * B_SZ)   // 8192
#define QSCALE 0.18033688011112042f   // 0.125 * log2(e)

__device__ __forceinline__ u16 f2b(float f) {
    unsigned u = __builtin_bit_cast(unsigned, f);
    u += 0x7fffu + ((u >> 16) & 1u);               // RNE
    return (u16)(u >> 16);
}
__device__ __forceinline__ float b2f(u16 u) {
    u32 x = ((u32)u) << 16; return __builtin_bit_cast(float, x);
}
#if defined(__has_builtin)
#if __has_builtin(__builtin_amdgcn_cvt_pk_bf16_f32)
#define HAVE_PK_BF16 1
#endif
#if __has_builtin(__builtin_amdgcn_rcpf)
#define HAVE_RCPF 1
#endif
#endif
__device__ __forceinline__ u32 pk_trunc(float a, float b) {
#ifdef HAVE_PK_BF16
    typedef __bf16 bf2 __attribute__((ext_vector_type(2)));
    bf2 r = __builtin_amdgcn_cvt_pk_bf16_f32(a, b);
    return __builtin_bit_cast(u32, r);
#else
    u32 ua = __builtin_bit_cast(u32, a), ub = __builtin_bit_cast(u32, b);
    return (ua >> 16) | (ub & 0xffff0000u);
#endif
}
__device__ __forceinline__ float frcp(float x) {
#ifdef HAVE_RCPF
    return __builtin_amdgcn_rcpf(x);
#else
    return 1.0f / x;
#endif
}
__device__ __forceinline__ void gload_lds16(const u16* g, u16* l) {
    __builtin_amdgcn_global_load_lds((__attribute__((address_space(1))) void*)(u16*)g,
                                     (__attribute__((address_space(3))) void*)l, 16, 0, 0);
}
// tanh-GELU in sigmoid form (|err| < 1e-3, below bf16 rounding of the result)
__device__ __forceinline__ float gelu_f(float v) {
    float y2 = v * (1.5957691216f + 0.0713548576f * v * v);
    return v / (1.0f + __expf(-y2));
}

// ---------------------------------------------------------------- PE table (b,e) -> 2048 floats
__global__ __launch_bounds__(256) void pe_tab_k(float* __restrict__ pet) {
    int i = blockIdx.x * 256 + threadIdx.x;          // 2048
    int e = i & (E_DIM - 1);
    float t = (float)(i >> 9) + 1.0f;
    int ee = (e & 1) ? (e + 1) : e;
    float w = exp2f((-(float)ee / 512.0f) * 13.287712379549449f);
    pet[i] = (e & 1) ? cosf(t * w) : sinf(t * w);
}

__global__ __launch_bounds__(256) void pe_add_k(const float* __restrict__ x,
                                                const float* __restrict__ pet,
                                                u16* __restrict__ xpb) {
    int idx = (blockIdx.x * 256 + threadIdx.x) * 4;
    f4v v = *(const f4v*)(x + idx);
    f4v p = *(const f4v*)(pet + (idx & 2047));
    u16x4 o;
#pragma unroll
    for (int i = 0; i < 4; ++i) o[i] = f2b(v[i] + p[i]);
    *(u16x4*)(xpb + idx) = o;
}

__global__ __launch_bounds__(256) void conv4_k(const float* __restrict__ s1, u16* __restrict__ d1, int n1,
                                               const float* __restrict__ s2, u16* __restrict__ d2, int n2,
                                               const float* __restrict__ s3, u16* __restrict__ d3, int n3,
                                               const float* __restrict__ s4, u16* __restrict__ d4) {
    int o = (blockIdx.x * 256 + threadIdx.x) * 4;
    const float* s; u16* d;
    if (o < n1) { s = s1; d = d1; }
    else { o -= n1;
        if (o < n2) { s = s2; d = d2; }
        else { o -= n2;
            if (o < n3) { s = s3; d = d3; }
            else { o -= n3; s = s4; d = d4; } } }
    f4v v = *(const f4v*)(s + o);
    u16x4 q;
#pragma unroll
    for (int i = 0; i < 4; ++i) q[i] = f2b(v[i]);
    *(u16x4*)(d + o) = q;
}

// ---------------------------------------------------------------- LN combine (wave per row)
template <int NP, bool WRITEF, bool WRITEB>
__global__ __launch_bounds__(256)
void ln_c(const u16* __restrict__ p0, const u16* __restrict__ p1,
          const u16* __restrict__ p2, const u16* __restrict__ p3,
          const float* __restrict__ bias, const u16* __restrict__ resid,
          const float* __restrict__ gw, const float* __restrict__ bw,
          float* __restrict__ outF, u16* __restrict__ outB) {
    int wave = threadIdx.x >> 6, lane = threadIdx.x & 63;
    size_t row = (size_t)blockIdx.x * 4 + wave;
    size_t off = row * E_DIM + lane * 8;
    u16x8 rv = *(const u16x8*)(resid + off);
    f4v a, b;
#pragma unroll
    for (int i = 0; i < 4; ++i) { a[i] = b2f(rv[i]); b[i] = b2f(rv[i + 4]); }
    a += *(const f4v*)(bias + lane * 8);
    b += *(const f4v*)(bias + lane * 8 + 4);
    const u16* ps[4] = {p0, p1, p2, p3};
#pragma unroll
    for (int z = 0; z < NP; ++z) {
        u16x8 t = *(const u16x8*)(ps[z] + off);
#pragma unroll
        for (int i = 0; i < 4; ++i) { a[i] += b2f(t[i]); b[i] += b2f(t[i + 4]); }
    }
    float s = (a[0] + a[1]) + (a[2] + a[3]) + (b[0] + b[1]) + (b[2] + b[3]);
#pragma unroll
    for (int o = 1; o < 64; o <<= 1) s += __shfl_xor(s, o, 64);
    float mu = s * (1.0f / E_DIM);
    float q = 0.f;
#pragma unroll
    for (int i = 0; i < 4; ++i) { float d = a[i] - mu; q += d * d; }
#pragma unroll
    for (int i = 0; i < 4; ++i) { float d = b[i] - mu; q += d * d; }
#pragma unroll
    for (int o = 1; o < 64; o <<= 1) q += __shfl_xor(q, o, 64);
    float rstd = rsqrtf(q * (1.0f / E_DIM) + 1e-5f);
    f4v g0 = *(const f4v*)(gw + lane * 8), g1 = *(const f4v*)(gw + lane * 8 + 4);
    f4v w0 = *(const f4v*)(bw + lane * 8), w1 = *(const f4v*)(bw + lane * 8 + 4);
    f4v y0, y1;
#pragma unroll
    for (int i = 0; i < 4; ++i) { y0[i] = (a[i] - mu) * rstd * g0[i] + w0[i];
                                  y1[i] = (b[i] - mu) * rstd * g1[i] + w1[i]; }
    if (WRITEF) {
        *(f4v*)(outF + off)     = y0;
        *(f4v*)(outF + off + 4) = y1;
    }
    if (WRITEB) {
        u16x8 o;
#pragma unroll
        for (int i = 0; i < 4; ++i) { o[i] = f2b(y0[i]); o[i + 4] = f2b(y1[i]); }
        *(u16x8*)(outB + off) = o;
    }
}

// ---------------------------------------------------------------- V transpose [b][h][l][d] -> [b][h][d][l]
__global__ __launch_bounds__(256) void transpose_v_k(const u16* __restrict__ vb,
                                                     u16* __restrict__ vt) {
    __shared__ __align__(16) u16 T[64 * 66];
    int t = threadIdx.x;
    int lt = blockIdx.x, bh = blockIdx.y;
    const u16* src = vb + (size_t)bh * (L_SEQ * HD) + (size_t)lt * 64 * HD;
    int lr = t >> 2, d0 = (t & 3) * 16;
    s8v va = *(const s8v*)(src + lr * HD + d0);
    s8v vb8 = *(const s8v*)(src + lr * HD + d0 + 8);
#pragma unroll
    for (int c = 0; c < 4; ++c) {
        u16x2 p0; p0[0] = (u16)va[c * 2]; p0[1] = (u16)va[c * 2 + 1];
        u16x2 p1; p1[0] = (u16)vb8[c * 2]; p1[1] = (u16)vb8[c * 2 + 1];
        *(u16x2*)(&T[lr * 66 + d0 + c * 2])     = p0;
        *(u16x2*)(&T[lr * 66 + d0 + 8 + c * 2]) = p1;
    }
    __syncthreads();
    int d = t >> 2, l0 = (t & 3) * 16;
    u16 tmp[16];
#pragma unroll
    for (int i = 0; i < 16; ++i) tmp[i] = T[(l0 + i) * 66 + d];
    u16* dst = vt + (size_t)bh * (L_SEQ * HD) + (size_t)d * L_SEQ + lt * 64 + l0;
    u16x8 o0, o1;
#pragma unroll
    for (int i = 0; i < 8; ++i) { o0[i] = tmp[i]; o1[i] = tmp[8 + i]; }
    *(u16x8*)dst       = o0;
    *(u16x8*)(dst + 8) = o1;
}

// ---------------------------------------------------------------- GEMM 128x128 BK32 dbuf + XCD swizzle (R14-proven)
// NT = n-tiles. MODE 0: QKV scatter (Q pre-scaled); MODE 2: tanh-GELU bf16.
template <int MODE, int NT>
__global__ __launch_bounds__(256, 4)
void gemm_bt(const u16* __restrict__ A, const u16* __restrict__ Bw,
             const float* __restrict__ bias, int M, int N, int K,
             u16* __restrict__ outB,
             u16* __restrict__ oq, u16* __restrict__ okk, u16* __restrict__ ov) {
    __shared__ __align__(16) u16 As[2][128 * 32];
    __shared__ __align__(16) u16 Bs[2][128 * 32];
    const int tid = threadIdx.x;
    const int wave = tid >> 6, lane = tid & 63;
    const int col = lane & 15, quad = lane >> 4;
    const int n = blockIdx.x;
    const int xcd = n & 7, loc = n >> 3;
    const int mpx = (M / 128) >> 3;
    const int bm = (xcd * mpx + loc / NT) * 128;
    const int bn = (loc % NT) * 128;
    const int wm = (wave >> 1) * 64, wn = (wave & 1) * 64;
    f4v acc[4][4] = {};
    const int srow = wave * 16 + (lane >> 2);
    const int soff = (lane & 3) * 8;
    const u16* Ag = A + (size_t)(bm + srow) * K + soff;
    const u16* Bg = Bw + (size_t)(bn + srow) * K + soff;
    const int wo = wave * 512;
    gload_lds16(Ag,                  &As[0][wo]);
    gload_lds16(Ag + (size_t)64 * K, &As[0][wo + 2048]);
    gload_lds16(Bg,                  &Bs[0][wo]);
    gload_lds16(Bg + (size_t)64 * K, &Bs[0][wo + 2048]);
    const int nit = K >> 5;
    for (int t = 0; t < nit; ++t) {
        const int cur = t & 1, nxt = cur ^ 1;
        __syncthreads();
        if (t + 1 < nit) {
            const int kc = (t + 1) * 32;
            gload_lds16(Ag + kc,                  &As[nxt][wo]);
            gload_lds16(Ag + (size_t)64 * K + kc, &As[nxt][wo + 2048]);
            gload_lds16(Bg + kc,                  &Bs[nxt][wo]);
            gload_lds16(Bg + (size_t)64 * K + kc, &Bs[nxt][wo + 2048]);
        }
        s8v af[4], bf[4];
#pragma unroll
        for (int i = 0; i < 4; ++i) af[i] = *(const s8v*)(&As[cur][(wm + i * 16 + col) * 32 + quad * 8]);
#pragma unroll
        for (int j = 0; j < 4; ++j) bf[j] = *(const s8v*)(&Bs[cur][(wn + j * 16 + col) * 32 + quad * 8]);
#pragma unroll
        for (int i = 0; i < 4; ++i)
#pragma unroll
            for (int j = 0; j < 4; ++j)
                acc[i][j] = __builtin_amdgcn_mfma_f32_16x16x32_bf16(af[i], bf[j], acc[i][j], 0, 0, 0);
    }
#pragma unroll
    for (int j = 0; j < 4; ++j) {
        int gn = bn + wn + j * 16 + col;
        float bv = bias[gn];
        int which = gn >> 9, hh = (gn >> 6) & 7, d = gn & 63;
        u16* dst = (MODE == 0) ? ((which == 0) ? oq : ((which == 1) ? okk : ov)) : outB;
        float qs = (MODE == 0 && which == 0) ? QSCALE : 1.0f;
#pragma unroll
        for (int i = 0; i < 4; ++i) {
            int gm0 = bm + wm + i * 16 + quad * 4;
#pragma unroll
            for (int r = 0; r < 4; ++r) {
                float v = acc[i][j][r] + bv;
                int m = gm0 + r;
                if (MODE == 2) {
                    outB[(size_t)m * N + gn] = f2b(gelu_f(v));
                } else {
                    int l = m >> 2, bb = m & 3;
                    dst[((size_t)(bb * H_CNT + hh) * L_SEQ + l) * HD + d] = f2b(v * qs);
                }
            }
        }
    }
}

// ---------------------------------------------------------------- K-split partial GEMM BK32 dbuf + XCD swizzle (R14)
__global__ __launch_bounds__(256, 4)
void gemm_ks(const u16* __restrict__ A, const u16* __restrict__ Bw,
             int N, int K, int Kper,
             u16* __restrict__ q0, u16* __restrict__ q1) {
    __shared__ __align__(16) u16 As[2][128 * 32];
    __shared__ __align__(16) u16 Bs[2][128 * 32];
    const int tid = threadIdx.x;
    const int wave = tid >> 6, lane = tid & 63;
    const int col = lane & 15, quad = lane >> 4;
    const int n = blockIdx.x;
    const int xcd = n & 7, loc = n >> 3;             // loc in [0,64)
    const int bn = (loc & 3) * 128;
    const int bm = (xcd * 8 + ((loc >> 2) & 7)) * 128;
    const int kz = loc >> 5;
    u16* pz = kz ? q1 : q0;
    const int wm = (wave >> 1) * 64, wn = (wave & 1) * 64;
    f4v acc[4][4] = {};
    const int srow = wave * 16 + (lane >> 2);
    const int soff = (lane & 3) * 8;
    const u16* Ag = A + (size_t)(bm + srow) * K + kz * Kper + soff;
    const u16* Bg = Bw + (size_t)(bn + srow) * K + kz * Kper + soff;
    const int wo = wave * 512;
    gload_lds16(Ag,                  &As[0][wo]);
    gload_lds16(Ag + (size_t)64 * K, &As[0][wo + 2048]);
    gload_lds16(Bg,                  &Bs[0][wo]);
    gload_lds16(Bg + (size_t)64 * K, &Bs[0][wo + 2048]);
    const int nit = Kper >> 5;
    for (int t = 0; t < nit; ++t) {
        const int cur = t & 1, nxt = cur ^ 1;
        __syncthreads();
        if (t + 1 < nit) {
            const int kc = (t + 1) * 32;
            gload_lds16(Ag + kc,                  &As[nxt][wo]);
            gload_lds16(Ag + (size_t)64 * K + kc, &As[nxt][wo + 2048]);
            gload_lds16(Bg + kc,                  &Bs[nxt][wo]);
            gload_lds16(Bg + (size_t)64 * K + kc, &Bs[nxt][wo + 2048]);
        }
        s8v af[4], bf[4];
#pragma unroll
        for (int i = 0; i < 4; ++i) af[i] = *(const s8v*)(&As[cur][(wm + i * 16 + col) * 32 + quad * 8]);
#pragma unroll
        for (int j = 0; j < 4; ++j) bf[j] = *(const s8v*)(&Bs[cur][(wn + j * 16 + col) * 32 + quad * 8]);
#pragma unroll
        for (int i = 0; i < 4; ++i)
#pragma unroll
            for (int j = 0; j < 4; ++j)
                acc[i][j] = __builtin_amdgcn_mfma_f32_16x16x32_bf16(af[i], bf[j], acc[i][j], 0, 0, 0);
    }
#pragma unroll
    for (int j = 0; j < 4; ++j) {
        int gn = bn + wn + j * 16 + col;
#pragma unroll
        for (int i = 0; i < 4; ++i) {
            int m0 = bm + wm + i * 16 + quad * 4;
#pragma unroll
            for (int r = 0; r < 4; ++r)
                pz[(size_t)(m0 + r) * N + gn] = f2b(acc[i][j][r]);
        }
    }
}

// ---------------------------------------------------------------- GEMM 256x256 BK32, 8 waves, 3-deep LDS ring,
// counted vmcnt (T3/T4), chunk XOR swizzle (T2), setprio (T5). K per block = 512 (16 tiles), XCD-chunked.
// MODE 2: bias+GELU->bf16. MODE 3: raw bf16 partial to o[kz].
// Swizzle: LDS chunk position (rho, g) holds global chunk g ^ ((rho>>1)&3); staged via inverse-permuted
// per-lane global source (dest stays linear, as global_load_lds requires); reads apply the same XOR.
#define G8_STAGE(Ad, Bd, kf)                                                           \
    {                                                                                  \
        _Pragma("unroll")                                                              \
        for (int s = 0; s < 2; ++s) {                                                  \
            const int q = (s * 8 + wave) * 64 + lane;                                  \
            const int rho = q >> 2;                                                    \
            gload_lds16(A  + (size_t)(bm + rho) * Ka + (kf) + gsw, (Ad) + q * 8);      \
            gload_lds16(Bw + (size_t)(bn + rho) * Kb + (kf) + gsw, (Bd) + q * 8);      \
        }                                                                              \
    }

#define G8_COMPUTE(Ab_, Bb_)                                                           \
    {                                                                                  \
        s8v bfr[4];                                                                    \
        _Pragma("unroll")                                                              \
        for (int j = 0; j < 4; ++j) {                                                  \
            const int rB = wc * 64 + j * 16 + col;                                     \
            bfr[j] = *(const s8v*)((Bb_) + rB * 32 + ((quad ^ ((rB >> 1) & 3)) * 8));  \
        }                                                                              \
        _Pragma("unroll")                                                              \
        for (int ih = 0; ih < 2; ++ih) {                                               \
            s8v afr[4];                                                                \
            _Pragma("unroll")                                                          \
            for (int i = 0; i < 4; ++i) {                                              \
                const int rA = wr * 128 + (ih * 4 + i) * 16 + col;                     \
                afr[i] = *(const s8v*)((Ab_) + rA * 32 + ((quad ^ ((rA >> 1) & 3)) * 8)); \
            }                                                                          \
            __builtin_amdgcn_s_setprio(1);                                             \
            _Pragma("unroll")                                                          \
            for (int i = 0; i < 4; ++i)                                                \
                _Pragma("unroll")                                                      \
                for (int j = 0; j < 4; ++j)                                            \
                    acc[ih * 4 + i][j] = __builtin_amdgcn_mfma_f32_16x16x32_bf16(afr[i], bfr[j], acc[ih * 4 + i][j], 0, 0, 0); \
            __builtin_amdgcn_s_setprio(0);                                             \
        }                                                                              \
    }

template <int MODE, int NTL, int KZL>
__global__ __launch_bounds__(512, 2)
void gemm8(const u16* __restrict__ A, const u16* __restrict__ Bw,
           const float* __restrict__ bias, int Ka, int Kb, int N,
           u16* __restrict__ o0, u16* __restrict__ o1,
           u16* __restrict__ o2, u16* __restrict__ o3) {
    extern __shared__ __align__(16) u16 LDS[];       // 3 x (A 8192 + B 8192) u16 = 96 KB
    const int tid = threadIdx.x;
    const int wave = tid >> 6, lane = tid & 63;
    const int col = lane & 15, quad = lane >> 4;
    const int wr = wave >> 2, wc = wave & 3;
    const int n = blockIdx.x;
    const int xcd = n & 7, loc = n >> 3;             // loc in [0,32)
    const int mt = xcd * 4 + (loc & 3);
    const int rest = loc >> 2;                       // [0,8)
    const int nt = (NTL == 1) ? 0 : (rest % NTL);
    const int kz = (KZL == 1) ? 0 : (rest / NTL);
    const int bm = mt * 256, bn = nt * 256;
    const int koff0 = kz * 512;
    const int gsw = ((lane & 3) ^ ((lane >> 3) & 3)) * 8;
    f4v acc[8][4] = {};
    u16* A0 = LDS;          u16* B0 = LDS + 8192;
    u16* A1 = LDS + 16384;  u16* B1 = LDS + 24576;
    u16* A2 = LDS + 32768;  u16* B2 = LDS + 40960;
    G8_STAGE(A0, B0, koff0);
    G8_STAGE(A1, B1, koff0 + 32);
    asm volatile("s_waitcnt vmcnt(4)" ::: "memory");
    __builtin_amdgcn_s_barrier();
    __builtin_amdgcn_sched_barrier(0);
    for (int t = 0; t < 14; ++t) {
        G8_STAGE(A2, B2, koff0 + (t + 2) * 32);
        G8_COMPUTE(A0, B0);
        asm volatile("s_waitcnt vmcnt(4)" ::: "memory");
        __builtin_amdgcn_s_barrier();
        __builtin_amdgcn_sched_barrier(0);
        u16* ta = A0; A0 = A1; A1 = A2; A2 = ta;
        u16* tb = B0; B0 = B1; B1 = B2; B2 = tb;
    }
    G8_COMPUTE(A0, B0);                               // tile 14
    asm volatile("s_waitcnt vmcnt(0)" ::: "memory");
    __builtin_amdgcn_s_barrier();
    __builtin_amdgcn_sched_barrier(0);
    G8_COMPUTE(A1, B1);                               // tile 15
    u16* outp = (MODE == 2) ? o0 : ((kz == 0) ? o0 : (kz == 1) ? o1 : (kz == 2) ? o2 : o3);
#pragma unroll
    for (int j = 0; j < 4; ++j) {
        const int gn = bn + wc * 64 + j * 16 + col;
        const float bv = (MODE == 2) ? bias[gn] : 0.0f;
#pragma unroll
        for (int i = 0; i < 8; ++i) {
            const int m0 = bm + wr * 128 + i * 16 + quad * 4;
#pragma unroll
            for (int r = 0; r < 4; ++r) {
                float v = acc[i][j][r] + bv;
                outp[(size_t)(m0 + r) * N + gn] = f2b(MODE == 2 ? gelu_f(v) : v);
            }
        }
    }
}

// ---------------------------------------------------------------- flash attention v12 (proven 45.4us):
// all-K32 MFMA, VALU l-sum, in-register normalization, XCD-chunked (K/V L2-resident).
__global__ __launch_bounds__(256, 4)
void attn_k(const u16* __restrict__ qg, const u16* __restrict__ kg,
            const u16* __restrict__ vtg, u16* __restrict__ og) {
    __shared__ __align__(16) u16 Ks[2][2][64 * 32];
    __shared__ __align__(16) u16 Vs[2][2][64 * 32];
    const int tid = threadIdx.x;
    const int wave = tid >> 6, lane = tid & 63;
    const int col = lane & 15, quad = lane >> 4;
    const int flat = blockIdx.x;
    const int xcd = flat & 7, loc = flat >> 3;       // loc in [0,64)
    const int bh = xcd * 4 + (loc >> 4);             // 4 heads per XCD
    const int qc = loc & 15;
    const size_t base = (size_t)bh * (L_SEQ * HD);
    s8v qf[2][2];
#pragma unroll
    for (int t = 0; t < 2; ++t) {
        const int qrow = qc * 128 + wave * 32 + t * 16 + col;
#pragma unroll
        for (int hh = 0; hh < 2; ++hh)
            qf[t][hh] = *(const s8v*)(qg + base + (size_t)qrow * HD + hh * 32 + quad * 8);
    }
    f4v oa[2][4] = {};
    float ls0 = 0.f, ls1 = 0.f;
    const int h = wave & 1, r0 = (wave >> 1) * 16;
    const int srow = lane >> 2, c = lane & 3;
    const int cp = c ^ ((srow >> 1) & 3);            // XOR-swizzled 16B chunk fetch
    // sigma row permutation: LDS row rho holds K-row 32*(rho>>5)+8*((rho>>2)&3)+4*((rho>>4)&1)+(rho&3)
    const int sig = ((srow >> 2) << 3) + ((r0 >> 4) << 2) + (srow & 3);
    const u16* Kg = kg + base + (size_t)sig * HD + h * 32 + cp * 8;
    const u16* Vg = vtg + base + (size_t)(r0 + srow) * L_SEQ + h * 32 + cp * 8;
    {
        gload_lds16(Kg,                      &Ks[0][h][r0 * 32]);
        gload_lds16(Kg + (size_t)32 * HD,    &Ks[0][h][(r0 + 32) * 32]);
        gload_lds16(Vg,                      &Vs[0][h][r0 * 32]);
        gload_lds16(Vg + (size_t)32 * L_SEQ, &Vs[0][h][(r0 + 32) * 32]);
    }
    const int perm = (col >> 1) & 3;
    for (int it = 0; it < 32; ++it) {
        const int cur = it & 1, nxt = cur ^ 1;
        __syncthreads();
        if (it + 1 < 32) {
            const int kv0 = (it + 1) * 64;
            gload_lds16(Kg + (size_t)kv0 * HD,         &Ks[nxt][h][r0 * 32]);
            gload_lds16(Kg + (size_t)(kv0 + 32) * HD,  &Ks[nxt][h][(r0 + 32) * 32]);
            gload_lds16(Vg + kv0,                      &Vs[nxt][h][r0 * 32]);
            gload_lds16(Vg + kv0 + (size_t)32 * L_SEQ, &Vs[nxt][h][(r0 + 32) * 32]);
        }
        f4v st[2][4];
#pragma unroll
        for (int j = 0; j < 4; ++j) {
            s8v k0 = *(const s8v*)(&Ks[cur][0][(j * 16 + col) * 32 + ((quad ^ perm) * 8)]);
            s8v k1 = *(const s8v*)(&Ks[cur][1][(j * 16 + col) * 32 + ((quad ^ perm) * 8)]);
#pragma unroll
            for (int t = 0; t < 2; ++t) {
                f4v z = {};
                z = __builtin_amdgcn_mfma_f32_16x16x32_bf16(k0, qf[t][0], z, 0, 0, 0);
                z = __builtin_amdgcn_mfma_f32_16x16x32_bf16(k1, qf[t][1], z, 0, 0, 0);
                st[t][j] = z;
            }
        }
        u32 pk[2][4][2];
#pragma unroll
        for (int t = 0; t < 2; ++t)
#pragma unroll
            for (int j = 0; j < 4; ++j) {
                f4v p;
#pragma unroll
                for (int r = 0; r < 4; ++r) p[r] = __builtin_amdgcn_exp2f(st[t][j][r]);
                float psum = (p[0] + p[1]) + (p[2] + p[3]);
                if (t == 0) ls0 += psum; else ls1 += psum;
                pk[t][j][0] = pk_trunc(p[0], p[1]);
                pk[t][j][1] = pk_trunc(p[2], p[3]);
            }
#pragma unroll
        for (int c2 = 0; c2 < 2; ++c2) {
            s8v pf[2];
#pragma unroll
            for (int t = 0; t < 2; ++t) {
                u32x4 q4 = {pk[t][2 * c2][0], pk[t][2 * c2][1],
                            pk[t][2 * c2 + 1][0], pk[t][2 * c2 + 1][1]};
                pf[t] = __builtin_bit_cast(s8v, q4);
            }
#pragma unroll
            for (int dj = 0; dj < 4; ++dj) {
                s8v vf = *(const s8v*)(&Vs[cur][c2][(dj * 16 + col) * 32 + ((quad ^ perm) * 8)]);
#pragma unroll
                for (int t = 0; t < 2; ++t)
                    oa[t][dj] = __builtin_amdgcn_mfma_f32_16x16x32_bf16(pf[t], vf, oa[t][dj], 0, 0, 0);
            }
        }
    }
    // complete l over quads (lanes sharing col), then normalize + write final O
    ls0 += __shfl_xor(ls0, 16, 64); ls0 += __shfl_xor(ls0, 32, 64);
    ls1 += __shfl_xor(ls1, 16, 64); ls1 += __shfl_xor(ls1, 32, 64);
    const int b = bh >> 3, hd = bh & 7;
#pragma unroll
    for (int t = 0; t < 2; ++t)
#pragma unroll
        for (int r = 0; r < 4; ++r) {
            float lv = __shfl(t == 0 ? ls0 : ls1, quad * 4 + r, 64);
            float inv = frcp(lv);
            int lrow = qc * 128 + wave * 32 + t * 16 + quad * 4 + r;
            size_t mrow = (size_t)(lrow * 4 + b) * E_DIM + hd * HD;
#pragma unroll
            for (int dj = 0; dj < 4; ++dj)
                og[mrow + dj * 16 + col] = f2b(oa[t][dj][r] * inv);
        }
}

// ---------------------------------------------------------------- host
extern "C" void kernel_launch(void* const* d_in, const int* in_sizes, int n_in,
                              void* d_out, int out_size, void* d_ws, size_t ws_size,
                              hipStream_t stream) {
    const float* x     = (const float*)d_in[0];
    const float* w_qkv = (const float*)d_in[1];
    const float* b_qkv = (const float*)d_in[2];
    const float* w_out = (const float*)d_in[3];
    const float* b_out = (const float*)d_in[4];
    const float* w1    = (const float*)d_in[5];
    const float* b1    = (const float*)d_in[6];
    const float* w2    = (const float*)d_in[7];
    const float* b2    = (const float*)d_in[8];
    const float* ln_g  = (const float*)d_in[9];
    const float* ln_b  = (const float*)d_in[10];

    char* ws = (char*)d_ws;
    u16*   WQKV = (u16*)(ws + 0);                    // 1.5 MB
    u16*   WOUT = (u16*)(ws + 1572864);              // 0.5 MB
    u16*   W1B  = (u16*)(ws + 2097152);              // 2 MB
    u16*   W2B  = (u16*)(ws + 4194304);              // 2 MB
    u16*   XPB  = (u16*)(ws + 6291456);              // 8 MB  x+pe bf16 (resid 1)
    u16*   QB   = (u16*)(ws + 14680064);             // 8 MB
    u16*   KB   = (u16*)(ws + 23068672);             // 8 MB
    u16*   VB   = (u16*)(ws + 31457280);             // 8 MB
    u16*   VT   = (u16*)(ws + 39845888);             // 8 MB
    float* PET  = (float*)(ws + 82837504);           // 8 KB PE table
    // aliases (disjoint lifetimes):
    u16*   OB   = VB;                                // attn out (VB free after transpose)
    u16*   OP0  = (u16*)(ws + 48234496);             // out-proj partials
    u16*   OP1  = (u16*)(ws + 56623104);
    u16*   X3B  = QB;                                // LN1 out bf16 (QB free after attn; resid 2)
    u16*   HB   = (u16*)(ws + 48234496);             // FFN1 out 32MB (over OPx, free after ln_c)
    u16*   FP0  = XPB;                               // FFN2 partials (XPB/KB/VB/VT all dead here)
    u16*   FP1  = KB;
    u16*   FP2  = VB;
    u16*   FP3  = VT;

    static bool attr_done = false;
    if (!attr_done) {
        hipFuncSetAttribute((const void*)gemm8<2, 8, 1>,
                            hipFuncAttributeMaxDynamicSharedMemorySize, 98304);
        hipFuncSetAttribute((const void*)gemm8<3, 2, 4>,
                            hipFuncAttributeMaxDynamicSharedMemorySize, 98304);
        attr_done = true;
    }

    pe_tab_k<<<8, 256, 0, stream>>>(PET);
    pe_add_k<<<4096, 256, 0, stream>>>(x, PET, XPB);
    conv4_k<<<3072, 256, 0, stream>>>(w_qkv, WQKV, 3 * E_DIM * E_DIM,
                                      w_out, WOUT, E_DIM * E_DIM,
                                      w1, W1B, HID * E_DIM,
                                      w2, W2B);
    gemm_bt<0, 12><<<768, 256, 0, stream>>>(XPB, WQKV, b_qkv, M_ROWS, 3 * E_DIM, E_DIM,
                                            nullptr, QB, KB, VB);
    transpose_v_k<<<dim3(32, 32), 256, 0, stream>>>(VB, VT);
    attn_k<<<512, 256, 0, stream>>>(QB, KB, VT, OB);
    gemm_ks<<<512, 256, 0, stream>>>(OB, WOUT, E_DIM, E_DIM, 256, OP0, OP1);
    ln_c<2, false, true><<<2048, 256, 0, stream>>>(OP0, OP1, nullptr, nullptr,
                                                   b_out, XPB, ln_g, ln_b, nullptr, X3B);
    gemm8<2, 8, 1><<<256, 512, 98304, stream>>>(X3B, W1B, b1, E_DIM, E_DIM, HID,
                                                HB, nullptr, nullptr, nullptr);
    gemm8<3, 2, 4><<<256, 512, 98304, stream>>>(HB, W2B, nullptr, HID, HID, E_DIM,
                                                FP0, FP1, FP2, FP3);
    ln_c<4, true, false><<<2048, 256, 0, stream>>>(FP0, FP1, FP2, FP3,
                                                   b2, X3B, ln_g, ln_b, (float*)d_out, nullptr);
}

// Round 8
// 242.198 us; speedup vs baseline: 1.0302x; 1.0302x over previous
//
#include <hip/hip_runtime.h>

typedef unsigned short u16;
typedef unsigned int   u32;
typedef u16  u16x2 __attribute__((ext_vector_type(2)));
typedef u16  u16x4 __attribute__((ext_vector_type(4)));
typedef u16  u16x8 __attribute__((ext_vector_type(8)));
typedef short s8v  __attribute__((ext_vector_type(8)));   // 8 bf16, MFMA A/B frag (K=32 shapes)
typedef float f4v  __attribute__((ext_vector_type(4)));   // MFMA C/D frag
typedef u32  u32x2 __attribute__((ext_vector_type(2)));
typedef u32  u32x4 __attribute__((ext_vector_type(4)));

#define L_SEQ 2048
#define B_SZ  4
#define E_DIM 512
#define H_CNT 8
#define HD    64
#define HID   2048
#define M_ROWS (L_SEQ * B_SZ)   // 8192
#define QSCALE 0.18033688011112042f   // 0.125 * log2(e)

__device__ __forceinline__ u16 f2b(float f) {
    unsigned u = __builtin_bit_cast(unsigned, f);
    u += 0x7fffu + ((u >> 16) & 1u);               // RNE
    return (u16)(u >> 16);
}
__device__ __forceinline__ float b2f(u16 u) {
    u32 x = ((u32)u) << 16; return __builtin_bit_cast(float, x);
}
#if defined(__has_builtin)
#if __has_builtin(__builtin_amdgcn_cvt_pk_bf16_f32)
#define HAVE_PK_BF16 1
#endif
#if __has_builtin(__builtin_amdgcn_rcpf)
#define HAVE_RCPF 1
#endif
#endif
__device__ __forceinline__ u32 pk_trunc(float a, float b) {
#ifdef HAVE_PK_BF16
    typedef __bf16 bf2 __attribute__((ext_vector_type(2)));
    bf2 r = __builtin_amdgcn_cvt_pk_bf16_f32(a, b);
    return __builtin_bit_cast(u32, r);
#else
    u32 ua = __builtin_bit_cast(u32, a), ub = __builtin_bit_cast(u32, b);
    return (ua >> 16) | (ub & 0xffff0000u);
#endif
}
__device__ __forceinline__ float frcp(float x) {
#ifdef HAVE_RCPF
    return __builtin_amdgcn_rcpf(x);
#else
    return 1.0f / x;
#endif
}
__device__ __forceinline__ void gload_lds16(const u16* g, u16* l) {
    __builtin_amdgcn_global_load_lds((__attribute__((address_space(1))) void*)(u16*)g,
                                     (__attribute__((address_space(3))) void*)l, 16, 0, 0);
}
// tanh-GELU in sigmoid form (|err| < 1e-3, below bf16 rounding of the result)
__device__ __forceinline__ float gelu_f(float v) {
    float y2 = v * (1.5957691216f + 0.0713548576f * v * v);
    return v / (1.0f + __expf(-y2));
}

// ---------------------------------------------------------------- PE table (b,e) -> 2048 floats
__global__ __launch_bounds__(256) void pe_tab_k(float* __restrict__ pet) {
    int i = blockIdx.x * 256 + threadIdx.x;          // 2048
    int e = i & (E_DIM - 1);
    float t = (float)(i >> 9) + 1.0f;
    int ee = (e & 1) ? (e + 1) : e;
    float w = exp2f((-(float)ee / 512.0f) * 13.287712379549449f);
    pet[i] = (e & 1) ? cosf(t * w) : sinf(t * w);
}

__global__ __launch_bounds__(256) void pe_add_k(const float* __restrict__ x,
                                                const float* __restrict__ pet,
                                                u16* __restrict__ xpb) {
    int idx = (blockIdx.x * 256 + threadIdx.x) * 4;
    f4v v = *(const f4v*)(x + idx);
    f4v p = *(const f4v*)(pet + (idx & 2047));
    u16x4 o;
#pragma unroll
    for (int i = 0; i < 4; ++i) o[i] = f2b(v[i] + p[i]);
    *(u16x4*)(xpb + idx) = o;
}

__global__ __launch_bounds__(256) void conv4_k(const float* __restrict__ s1, u16* __restrict__ d1, int n1,
                                               const float* __restrict__ s2, u16* __restrict__ d2, int n2,
                                               const float* __restrict__ s3, u16* __restrict__ d3, int n3,
                                               const float* __restrict__ s4, u16* __restrict__ d4) {
    int o = (blockIdx.x * 256 + threadIdx.x) * 4;
    const float* s; u16* d;
    if (o < n1) { s = s1; d = d1; }
    else { o -= n1;
        if (o < n2) { s = s2; d = d2; }
        else { o -= n2;
            if (o < n3) { s = s3; d = d3; }
            else { o -= n3; s = s4; d = d4; } } }
    f4v v = *(const f4v*)(s + o);
    u16x4 q;
#pragma unroll
    for (int i = 0; i < 4; ++i) q[i] = f2b(v[i]);
    *(u16x4*)(d + o) = q;
}

// ---------------------------------------------------------------- LN combine (wave per row)
template <int NP, bool WRITEF, bool WRITEB>
__global__ __launch_bounds__(256)
void ln_c(const u16* __restrict__ p0, const u16* __restrict__ p1,
          const u16* __restrict__ p2, const u16* __restrict__ p3,
          const float* __restrict__ bias, const u16* __restrict__ resid,
          const float* __restrict__ gw, const float* __restrict__ bw,
          float* __restrict__ outF, u16* __restrict__ outB) {
    int wave = threadIdx.x >> 6, lane = threadIdx.x & 63;
    size_t row = (size_t)blockIdx.x * 4 + wave;
    size_t off = row * E_DIM + lane * 8;
    u16x8 rv = *(const u16x8*)(resid + off);
    f4v a, b;
#pragma unroll
    for (int i = 0; i < 4; ++i) { a[i] = b2f(rv[i]); b[i] = b2f(rv[i + 4]); }
    a += *(const f4v*)(bias + lane * 8);
    b += *(const f4v*)(bias + lane * 8 + 4);
    const u16* ps[4] = {p0, p1, p2, p3};
#pragma unroll
    for (int z = 0; z < NP; ++z) {
        u16x8 t = *(const u16x8*)(ps[z] + off);
#pragma unroll
        for (int i = 0; i < 4; ++i) { a[i] += b2f(t[i]); b[i] += b2f(t[i + 4]); }
    }
    float s = (a[0] + a[1]) + (a[2] + a[3]) + (b[0] + b[1]) + (b[2] + b[3]);
#pragma unroll
    for (int o = 1; o < 64; o <<= 1) s += __shfl_xor(s, o, 64);
    float mu = s * (1.0f / E_DIM);
    float q = 0.f;
#pragma unroll
    for (int i = 0; i < 4; ++i) { float d = a[i] - mu; q += d * d; }
#pragma unroll
    for (int i = 0; i < 4; ++i) { float d = b[i] - mu; q += d * d; }
#pragma unroll
    for (int o = 1; o < 64; o <<= 1) q += __shfl_xor(q, o, 64);
    float rstd = rsqrtf(q * (1.0f / E_DIM) + 1e-5f);
    f4v g0 = *(const f4v*)(gw + lane * 8), g1 = *(const f4v*)(gw + lane * 8 + 4);
    f4v w0 = *(const f4v*)(bw + lane * 8), w1 = *(const f4v*)(bw + lane * 8 + 4);
    f4v y0, y1;
#pragma unroll
    for (int i = 0; i < 4; ++i) { y0[i] = (a[i] - mu) * rstd * g0[i] + w0[i];
                                  y1[i] = (b[i] - mu) * rstd * g1[i] + w1[i]; }
    if (WRITEF) {
        *(f4v*)(outF + off)     = y0;
        *(f4v*)(outF + off + 4) = y1;
    }
    if (WRITEB) {
        u16x8 o;
#pragma unroll
        for (int i = 0; i < 4; ++i) { o[i] = f2b(y0[i]); o[i + 4] = f2b(y1[i]); }
        *(u16x8*)(outB + off) = o;
    }
}

// ---------------------------------------------------------------- V transpose [b][h][l][d] -> [b][h][d][l]
__global__ __launch_bounds__(256) void transpose_v_k(const u16* __restrict__ vb,
                                                     u16* __restrict__ vt) {
    __shared__ __align__(16) u16 T[64 * 66];
    int t = threadIdx.x;
    int lt = blockIdx.x, bh = blockIdx.y;
    const u16* src = vb + (size_t)bh * (L_SEQ * HD) + (size_t)lt * 64 * HD;
    int lr = t >> 2, d0 = (t & 3) * 16;
    s8v va = *(const s8v*)(src + lr * HD + d0);
    s8v vb8 = *(const s8v*)(src + lr * HD + d0 + 8);
#pragma unroll
    for (int c = 0; c < 4; ++c) {
        u16x2 p0; p0[0] = (u16)va[c * 2]; p0[1] = (u16)va[c * 2 + 1];
        u16x2 p1; p1[0] = (u16)vb8[c * 2]; p1[1] = (u16)vb8[c * 2 + 1];
        *(u16x2*)(&T[lr * 66 + d0 + c * 2])     = p0;
        *(u16x2*)(&T[lr * 66 + d0 + 8 + c * 2]) = p1;
    }
    __syncthreads();
    int d = t >> 2, l0 = (t & 3) * 16;
    u16 tmp[16];
#pragma unroll
    for (int i = 0; i < 16; ++i) tmp[i] = T[(l0 + i) * 66 + d];
    u16* dst = vt + (size_t)bh * (L_SEQ * HD) + (size_t)d * L_SEQ + lt * 64 + l0;
    u16x8 o0, o1;
#pragma unroll
    for (int i = 0; i < 8; ++i) { o0[i] = tmp[i]; o1[i] = tmp[8 + i]; }
    *(u16x8*)dst       = o0;
    *(u16x8*)(dst + 8) = o1;
}

// ---------------------------------------------------------------- GEMM 128x128 BK32 dbuf + XCD swizzle (R14-proven)
// NT = n-tiles. MODE 0: QKV scatter (Q pre-scaled); MODE 2: tanh-GELU bf16.
template <int MODE, int NT>
__global__ __launch_bounds__(256, 4)
void gemm_bt(const u16* __restrict__ A, const u16* __restrict__ Bw,
             const float* __restrict__ bias, int M, int N, int K,
             u16* __restrict__ outB,
             u16* __restrict__ oq, u16* __restrict__ okk, u16* __restrict__ ov) {
    __shared__ __align__(16) u16 As[2][128 * 32];
    __shared__ __align__(16) u16 Bs[2][128 * 32];
    const int tid = threadIdx.x;
    const int wave = tid >> 6, lane = tid & 63;
    const int col = lane & 15, quad = lane >> 4;
    const int n = blockIdx.x;
    const int xcd = n & 7, loc = n >> 3;
    const int mpx = (M / 128) >> 3;
    const int bm = (xcd * mpx + loc / NT) * 128;
    const int bn = (loc % NT) * 128;
    const int wm = (wave >> 1) * 64, wn = (wave & 1) * 64;
    f4v acc[4][4] = {};
    const int srow = wave * 16 + (lane >> 2);
    const int soff = (lane & 3) * 8;
    const u16* Ag = A + (size_t)(bm + srow) * K + soff;
    const u16* Bg = Bw + (size_t)(bn + srow) * K + soff;
    const int wo = wave * 512;
    gload_lds16(Ag,                  &As[0][wo]);
    gload_lds16(Ag + (size_t)64 * K, &As[0][wo + 2048]);
    gload_lds16(Bg,                  &Bs[0][wo]);
    gload_lds16(Bg + (size_t)64 * K, &Bs[0][wo + 2048]);
    const int nit = K >> 5;
    for (int t = 0; t < nit; ++t) {
        const int cur = t & 1, nxt = cur ^ 1;
        __syncthreads();
        if (t + 1 < nit) {
            const int kc = (t + 1) * 32;
            gload_lds16(Ag + kc,                  &As[nxt][wo]);
            gload_lds16(Ag + (size_t)64 * K + kc, &As[nxt][wo + 2048]);
            gload_lds16(Bg + kc,                  &Bs[nxt][wo]);
            gload_lds16(Bg + (size_t)64 * K + kc, &Bs[nxt][wo + 2048]);
        }
        s8v af[4], bf[4];
#pragma unroll
        for (int i = 0; i < 4; ++i) af[i] = *(const s8v*)(&As[cur][(wm + i * 16 + col) * 32 + quad * 8]);
#pragma unroll
        for (int j = 0; j < 4; ++j) bf[j] = *(const s8v*)(&Bs[cur][(wn + j * 16 + col) * 32 + quad * 8]);
#pragma unroll
        for (int i = 0; i < 4; ++i)
#pragma unroll
            for (int j = 0; j < 4; ++j)
                acc[i][j] = __builtin_amdgcn_mfma_f32_16x16x32_bf16(af[i], bf[j], acc[i][j], 0, 0, 0);
    }
#pragma unroll
    for (int j = 0; j < 4; ++j) {
        int gn = bn + wn + j * 16 + col;
        float bv = bias[gn];
        int which = gn >> 9, hh = (gn >> 6) & 7, d = gn & 63;
        u16* dst = (MODE == 0) ? ((which == 0) ? oq : ((which == 1) ? okk : ov)) : outB;
        float qs = (MODE == 0 && which == 0) ? QSCALE : 1.0f;
#pragma unroll
        for (int i = 0; i < 4; ++i) {
            int gm0 = bm + wm + i * 16 + quad * 4;
#pragma unroll
            for (int r = 0; r < 4; ++r) {
                float v = acc[i][j][r] + bv;
                int m = gm0 + r;
                if (MODE == 2) {
                    outB[(size_t)m * N + gn] = f2b(gelu_f(v));
                } else {
                    int l = m >> 2, bb = m & 3;
                    dst[((size_t)(bb * H_CNT + hh) * L_SEQ + l) * HD + d] = f2b(v * qs);
                }
            }
        }
    }
}

// ---------------------------------------------------------------- K-split partial GEMM BK32 dbuf + XCD swizzle (R14)
__global__ __launch_bounds__(256, 4)
void gemm_ks(const u16* __restrict__ A, const u16* __restrict__ Bw,
             int N, int K, int Kper,
             u16* __restrict__ q0, u16* __restrict__ q1) {
    __shared__ __align__(16) u16 As[2][128 * 32];
    __shared__ __align__(16) u16 Bs[2][128 * 32];
    const int tid = threadIdx.x;
    const int wave = tid >> 6, lane = tid & 63;
    const int col = lane & 15, quad = lane >> 4;
    const int n = blockIdx.x;
    const int xcd = n & 7, loc = n >> 3;             // loc in [0,64)
    const int bn = (loc & 3) * 128;
    const int bm = (xcd * 8 + ((loc >> 2) & 7)) * 128;
    const int kz = loc >> 5;
    u16* pz = kz ? q1 : q0;
    const int wm = (wave >> 1) * 64, wn = (wave & 1) * 64;
    f4v acc[4][4] = {};
    const int srow = wave * 16 + (lane >> 2);
    const int soff = (lane & 3) * 8;
    const u16* Ag = A + (size_t)(bm + srow) * K + kz * Kper + soff;
    const u16* Bg = Bw + (size_t)(bn + srow) * K + kz * Kper + soff;
    const int wo = wave * 512;
    gload_lds16(Ag,                  &As[0][wo]);
    gload_lds16(Ag + (size_t)64 * K, &As[0][wo + 2048]);
    gload_lds16(Bg,                  &Bs[0][wo]);
    gload_lds16(Bg + (size_t)64 * K, &Bs[0][wo + 2048]);
    const int nit = Kper >> 5;
    for (int t = 0; t < nit; ++t) {
        const int cur = t & 1, nxt = cur ^ 1;
        __syncthreads();
        if (t + 1 < nit) {
            const int kc = (t + 1) * 32;
            gload_lds16(Ag + kc,                  &As[nxt][wo]);
            gload_lds16(Ag + (size_t)64 * K + kc, &As[nxt][wo + 2048]);
            gload_lds16(Bg + kc,                  &Bs[nxt][wo]);
            gload_lds16(Bg + (size_t)64 * K + kc, &Bs[nxt][wo + 2048]);
        }
        s8v af[4], bf[4];
#pragma unroll
        for (int i = 0; i < 4; ++i) af[i] = *(const s8v*)(&As[cur][(wm + i * 16 + col) * 32 + quad * 8]);
#pragma unroll
        for (int j = 0; j < 4; ++j) bf[j] = *(const s8v*)(&Bs[cur][(wn + j * 16 + col) * 32 + quad * 8]);
#pragma unroll
        for (int i = 0; i < 4; ++i)
#pragma unroll
            for (int j = 0; j < 4; ++j)
                acc[i][j] = __builtin_amdgcn_mfma_f32_16x16x32_bf16(af[i], bf[j], acc[i][j], 0, 0, 0);
    }
#pragma unroll
    for (int j = 0; j < 4; ++j) {
        int gn = bn + wn + j * 16 + col;
#pragma unroll
        for (int i = 0; i < 4; ++i) {
            int m0 = bm + wm + i * 16 + quad * 4;
#pragma unroll
            for (int r = 0; r < 4; ++r)
                pz[(size_t)(m0 + r) * N + gn] = f2b(acc[i][j][r]);
        }
    }
}

// ---------------------------------------------------------------- flash attention v13: v12 inner loop (proven),
// 8-wave blocks = 2 kv-groups x 4 waves. Group g runs kv tiles [g*16, g*16+16) with its own K/V dbuf;
// group 1 dumps fp32 oa/l partials into its (dead) K/V LDS region; group 0 adds, normalizes, writes.
// Doubles waves/CU (8 -> 16) at unchanged total MFMA/staging. Grid 512 = 16 qc x 32 bh, XCD-chunked.
__global__ __launch_bounds__(512, 4)
void attn_k(const u16* __restrict__ qg, const u16* __restrict__ kg,
            const u16* __restrict__ vtg, u16* __restrict__ og) {
    __shared__ __align__(16) u16 KV[2][2][2][2][64 * 32];   // [group][K/V][dbuf][h][.] = 64 KB
    __shared__ float LSB[2][256];                           // l partials, 2 KB
    const int tid = threadIdx.x;
    const int wave = tid >> 6, lane = tid & 63;
    const int grp = wave >> 2, w4 = wave & 3;
    const int col = lane & 15, quad = lane >> 4;
    const int flat = blockIdx.x;
    const int xcd = flat & 7, loc = flat >> 3;       // loc in [0,64)
    const int bh = xcd * 4 + (loc >> 4);             // 4 heads per XCD
    const int qc = loc & 15;
    const size_t base = (size_t)bh * (L_SEQ * HD);
    s8v qf[2][2];
#pragma unroll
    for (int t = 0; t < 2; ++t) {
        const int qrow = qc * 128 + w4 * 32 + t * 16 + col;
#pragma unroll
        for (int hh = 0; hh < 2; ++hh)
            qf[t][hh] = *(const s8v*)(qg + base + (size_t)qrow * HD + hh * 32 + quad * 8);
    }
    f4v oa[2][4] = {};
    float ls0 = 0.f, ls1 = 0.f;
    const int h = w4 & 1, r0 = (w4 >> 1) * 16;
    const int srow = lane >> 2, c = lane & 3;
    const int cp = c ^ ((srow >> 1) & 3);            // XOR-swizzled 16B chunk fetch
    // sigma row permutation: LDS row rho holds K-row 32*(rho>>5)+8*((rho>>2)&3)+4*((rho>>4)&1)+(rho&3)
    const int sig = ((srow >> 2) << 3) + ((r0 >> 4) << 2) + (srow & 3);
    const u16* Kg = kg + base + (size_t)(sig + grp * 1024) * HD + h * 32 + cp * 8;
    const u16* Vg = vtg + base + (size_t)(r0 + srow) * L_SEQ + grp * 1024 + h * 32 + cp * 8;
    {
        gload_lds16(Kg,                      &KV[grp][0][0][h][r0 * 32]);
        gload_lds16(Kg + (size_t)32 * HD,    &KV[grp][0][0][h][(r0 + 32) * 32]);
        gload_lds16(Vg,                      &KV[grp][1][0][h][r0 * 32]);
        gload_lds16(Vg + (size_t)32 * L_SEQ, &KV[grp][1][0][h][(r0 + 32) * 32]);
    }
    const int perm = (col >> 1) & 3;
    for (int it = 0; it < 16; ++it) {
        const int cur = it & 1, nxt = cur ^ 1;
        __syncthreads();
        if (it + 1 < 16) {
            const int kv0 = (it + 1) * 64;
            gload_lds16(Kg + (size_t)kv0 * HD,         &KV[grp][0][nxt][h][r0 * 32]);
            gload_lds16(Kg + (size_t)(kv0 + 32) * HD,  &KV[grp][0][nxt][h][(r0 + 32) * 32]);
            gload_lds16(Vg + kv0,                      &KV[grp][1][nxt][h][r0 * 32]);
            gload_lds16(Vg + kv0 + (size_t)32 * L_SEQ, &KV[grp][1][nxt][h][(r0 + 32) * 32]);
        }
        f4v st[2][4];
#pragma unroll
        for (int j = 0; j < 4; ++j) {
            s8v k0 = *(const s8v*)(&KV[grp][0][cur][0][(j * 16 + col) * 32 + ((quad ^ perm) * 8)]);
            s8v k1 = *(const s8v*)(&KV[grp][0][cur][1][(j * 16 + col) * 32 + ((quad ^ perm) * 8)]);
#pragma unroll
            for (int t = 0; t < 2; ++t) {
                f4v z = {};
                z = __builtin_amdgcn_mfma_f32_16x16x32_bf16(k0, qf[t][0], z, 0, 0, 0);
                z = __builtin_amdgcn_mfma_f32_16x16x32_bf16(k1, qf[t][1], z, 0, 0, 0);
                st[t][j] = z;
            }
        }
        u32 pk[2][4][2];
#pragma unroll
        for (int t = 0; t < 2; ++t)
#pragma unroll
            for (int j = 0; j < 4; ++j) {
                f4v p;
#pragma unroll
                for (int r = 0; r < 4; ++r) p[r] = __builtin_amdgcn_exp2f(st[t][j][r]);
                float psum = (p[0] + p[1]) + (p[2] + p[3]);
                if (t == 0) ls0 += psum; else ls1 += psum;
                pk[t][j][0] = pk_trunc(p[0], p[1]);
                pk[t][j][1] = pk_trunc(p[2], p[3]);
            }
#pragma unroll
        for (int c2 = 0; c2 < 2; ++c2) {
            s8v pf[2];
#pragma unroll
            for (int t = 0; t < 2; ++t) {
                u32x4 q4 = {pk[t][2 * c2][0], pk[t][2 * c2][1],
                            pk[t][2 * c2 + 1][0], pk[t][2 * c2 + 1][1]};
                pf[t] = __builtin_bit_cast(s8v, q4);
            }
#pragma unroll
            for (int dj = 0; dj < 4; ++dj) {
                s8v vf = *(const s8v*)(&KV[grp][1][cur][c2][(dj * 16 + col) * 32 + ((quad ^ perm) * 8)]);
#pragma unroll
                for (int t = 0; t < 2; ++t)
                    oa[t][dj] = __builtin_amdgcn_mfma_f32_16x16x32_bf16(pf[t], vf, oa[t][dj], 0, 0, 0);
            }
        }
    }
    // reduce l over quads within each group (lanes sharing col)
    ls0 += __shfl_xor(ls0, 16, 64); ls0 += __shfl_xor(ls0, 32, 64);
    ls1 += __shfl_xor(ls1, 16, 64); ls1 += __shfl_xor(ls1, 32, 64);
    // cross-group combine via group-1's (dead) K/V LDS region (exactly 32 KB)
    float* cmb = (float*)&KV[1][0][0][0][0];
    const int slot = w4 * 64 + lane;
    if (grp == 1) {
#pragma unroll
        for (int t = 0; t < 2; ++t)
#pragma unroll
            for (int dj = 0; dj < 4; ++dj)
                *(f4v*)(cmb + ((size_t)(t * 4 + dj) * 256 + slot) * 4) = oa[t][dj];
        LSB[0][slot] = ls0;
        LSB[1][slot] = ls1;
    }
    __syncthreads();
    if (grp == 0) {
#pragma unroll
        for (int t = 0; t < 2; ++t)
#pragma unroll
            for (int dj = 0; dj < 4; ++dj)
                oa[t][dj] += *(const f4v*)(cmb + ((size_t)(t * 4 + dj) * 256 + slot) * 4);
        ls0 += LSB[0][slot];
        ls1 += LSB[1][slot];
        const int b = bh >> 3, hd = bh & 7;
#pragma unroll
        for (int t = 0; t < 2; ++t)
#pragma unroll
            for (int r = 0; r < 4; ++r) {
                float lv = __shfl(t == 0 ? ls0 : ls1, quad * 4 + r, 64);
                float inv = frcp(lv);
                int lrow = qc * 128 + w4 * 32 + t * 16 + quad * 4 + r;
                size_t mrow = (size_t)(lrow * 4 + b) * E_DIM + hd * HD;
#pragma unroll
                for (int dj = 0; dj < 4; ++dj)
                    og[mrow + dj * 16 + col] = f2b(oa[t][dj][r] * inv);
            }
    }
}

// ---------------------------------------------------------------- host
extern "C" void kernel_launch(void* const* d_in, const int* in_sizes, int n_in,
                              void* d_out, int out_size, void* d_ws, size_t ws_size,
                              hipStream_t stream) {
    const float* x     = (const float*)d_in[0];
    const float* w_qkv = (const float*)d_in[1];
    const float* b_qkv = (const float*)d_in[2];
    const float* w_out = (const float*)d_in[3];
    const float* b_out = (const float*)d_in[4];
    const float* w1    = (const float*)d_in[5];
    const float* b1    = (const float*)d_in[6];
    const float* w2    = (const float*)d_in[7];
    const float* b2    = (const float*)d_in[8];
    const float* ln_g  = (const float*)d_in[9];
    const float* ln_b  = (const float*)d_in[10];

    char* ws = (char*)d_ws;
    u16*   WQKV = (u16*)(ws + 0);                    // 1.5 MB
    u16*   WOUT = (u16*)(ws + 1572864);              // 0.5 MB
    u16*   W1B  = (u16*)(ws + 2097152);              // 2 MB
    u16*   W2B  = (u16*)(ws + 4194304);              // 2 MB
    u16*   XPB  = (u16*)(ws + 6291456);              // 8 MB  x+pe bf16 (resid 1)
    u16*   QB   = (u16*)(ws + 14680064);             // 8 MB
    u16*   KB   = (u16*)(ws + 23068672);             // 8 MB
    u16*   VB   = (u16*)(ws + 31457280);             // 8 MB
    u16*   VT   = (u16*)(ws + 39845888);             // 8 MB
    float* PET  = (float*)(ws + 82837504);           // 8 KB PE table
    // aliases (disjoint lifetimes):
    u16*   OB   = VB;                                // attn out (VB free after transpose)
    u16*   OP0  = (u16*)(ws + 48234496);             // out-proj partials
    u16*   OP1  = (u16*)(ws + 56623104);
    u16*   X3B  = QB;                                // LN1 out bf16 (QB free after attn; resid 2)
    u16*   HB   = (u16*)(ws + 48234496);             // FFN1 out 32MB (over OPx, free after ln_c)
    u16*   FP0  = XPB;                               // FFN2 partials (free by FFN2)
    u16*   FP1  = KB;

    pe_tab_k<<<8, 256, 0, stream>>>(PET);
    pe_add_k<<<4096, 256, 0, stream>>>(x, PET, XPB);
    conv4_k<<<3072, 256, 0, stream>>>(w_qkv, WQKV, 3 * E_DIM * E_DIM,
                                      w_out, WOUT, E_DIM * E_DIM,
                                      w1, W1B, HID * E_DIM,
                                      w2, W2B);
    gemm_bt<0, 12><<<768, 256, 0, stream>>>(XPB, WQKV, b_qkv, M_ROWS, 3 * E_DIM, E_DIM,
                                            nullptr, QB, KB, VB);
    transpose_v_k<<<dim3(32, 32), 256, 0, stream>>>(VB, VT);
    attn_k<<<512, 512, 0, stream>>>(QB, KB, VT, OB);
    gemm_ks<<<512, 256, 0, stream>>>(OB, WOUT, E_DIM, E_DIM, 256, OP0, OP1);
    ln_c<2, false, true><<<2048, 256, 0, stream>>>(OP0, OP1, nullptr, nullptr,
                                                   b_out, XPB, ln_g, ln_b, nullptr, X3B);
    gemm_bt<2, 16><<<1024, 256, 0, stream>>>(X3B, W1B, b1, M_ROWS, HID, E_DIM,
                                             HB, nullptr, nullptr, nullptr);
    gemm_ks<<<512, 256, 0, stream>>>(HB, W2B, E_DIM, HID, 1024, FP0, FP1);
    ln_c<2, true, false><<<2048, 256, 0, stream>>>(FP0, FP1, nullptr, nullptr,
                                                   b2, X3B, ln_g, ln_b, (float*)d_out, nullptr);
}

// Round 9
// 239.280 us; speedup vs baseline: 1.0428x; 1.0122x over previous
//
#include <hip/hip_runtime.h>

typedef unsigned short u16;
typedef unsigned int   u32;
typedef u16  u16x2 __attribute__((ext_vector_type(2)));
typedef u16  u16x4 __attribute__((ext_vector_type(4)));
typedef u16  u16x8 __attribute__((ext_vector_type(8)));
typedef short s8v  __attribute__((ext_vector_type(8)));   // 8 bf16, MFMA A/B frag (K=32 shapes)
typedef float f4v  __attribute__((ext_vector_type(4)));   // MFMA C/D frag
typedef u32  u32x2 __attribute__((ext_vector_type(2)));
typedef u32  u32x4 __attribute__((ext_vector_type(4)));

#define L_SEQ 2048
#define B_SZ  4
#define E_DIM 512
#define H_CNT 8
#define HD    64
#define HID   2048
#define M_ROWS (L_SEQ * B_SZ)   // 8192
#define QSCALE 0.18033688011112042f   // 0.125 * log2(e)

__device__ __forceinline__ u16 f2b(float f) {
    unsigned u = __builtin_bit_cast(unsigned, f);
    u += 0x7fffu + ((u >> 16) & 1u);               // RNE
    return (u16)(u >> 16);
}
__device__ __forceinline__ float b2f(u16 u) {
    u32 x = ((u32)u) << 16; return __builtin_bit_cast(float, x);
}
#if defined(__has_builtin)
#if __has_builtin(__builtin_amdgcn_cvt_pk_bf16_f32)
#define HAVE_PK_BF16 1
#endif
#if __has_builtin(__builtin_amdgcn_rcpf)
#define HAVE_RCPF 1
#endif
#endif
__device__ __forceinline__ u32 pk_trunc(float a, float b) {
#ifdef HAVE_PK_BF16
    typedef __bf16 bf2 __attribute__((ext_vector_type(2)));
    bf2 r = __builtin_amdgcn_cvt_pk_bf16_f32(a, b);
    return __builtin_bit_cast(u32, r);
#else
    u32 ua = __builtin_bit_cast(u32, a), ub = __builtin_bit_cast(u32, b);
    return (ua >> 16) | (ub & 0xffff0000u);
#endif
}
__device__ __forceinline__ float frcp(float x) {
#ifdef HAVE_RCPF
    return __builtin_amdgcn_rcpf(x);
#else
    return 1.0f / x;
#endif
}
__device__ __forceinline__ void gload_lds16(const u16* g, u16* l) {
    __builtin_amdgcn_global_load_lds((__attribute__((address_space(1))) void*)(u16*)g,
                                     (__attribute__((address_space(3))) void*)l, 16, 0, 0);
}
// tanh-GELU in sigmoid form (|err| < 1e-3, below bf16 rounding of the result)
__device__ __forceinline__ float gelu_f(float v) {
    float y2 = v * (1.5957691216f + 0.0713548576f * v * v);
    return v / (1.0f + __expf(-y2));
}

// ---------------------------------------------------------------- PE table (b,e) -> 2048 floats
__global__ __launch_bounds__(256) void pe_tab_k(float* __restrict__ pet) {
    int i = blockIdx.x * 256 + threadIdx.x;          // 2048
    int e = i & (E_DIM - 1);
    float t = (float)(i >> 9) + 1.0f;
    int ee = (e & 1) ? (e + 1) : e;
    float w = exp2f((-(float)ee / 512.0f) * 13.287712379549449f);
    pet[i] = (e & 1) ? cosf(t * w) : sinf(t * w);
}

__global__ __launch_bounds__(256) void pe_add_k(const float* __restrict__ x,
                                                const float* __restrict__ pet,
                                                u16* __restrict__ xpb) {
    int idx = (blockIdx.x * 256 + threadIdx.x) * 4;
    f4v v = *(const f4v*)(x + idx);
    f4v p = *(const f4v*)(pet + (idx & 2047));
    u16x4 o;
#pragma unroll
    for (int i = 0; i < 4; ++i) o[i] = f2b(v[i] + p[i]);
    *(u16x4*)(xpb + idx) = o;
}

__global__ __launch_bounds__(256) void conv4_k(const float* __restrict__ s1, u16* __restrict__ d1, int n1,
                                               const float* __restrict__ s2, u16* __restrict__ d2, int n2,
                                               const float* __restrict__ s3, u16* __restrict__ d3, int n3,
                                               const float* __restrict__ s4, u16* __restrict__ d4) {
    int o = (blockIdx.x * 256 + threadIdx.x) * 4;
    const float* s; u16* d;
    if (o < n1) { s = s1; d = d1; }
    else { o -= n1;
        if (o < n2) { s = s2; d = d2; }
        else { o -= n2;
            if (o < n3) { s = s3; d = d3; }
            else { o -= n3; s = s4; d = d4; } } }
    f4v v = *(const f4v*)(s + o);
    u16x4 q;
#pragma unroll
    for (int i = 0; i < 4; ++i) q[i] = f2b(v[i]);
    *(u16x4*)(d + o) = q;
}

// ---------------------------------------------------------------- LN combine (wave per row)
template <int NP, bool WRITEF, bool WRITEB>
__global__ __launch_bounds__(256)
void ln_c(const u16* __restrict__ p0, const u16* __restrict__ p1,
          const u16* __restrict__ p2, const u16* __restrict__ p3,
          const float* __restrict__ bias, const u16* __restrict__ resid,
          const float* __restrict__ gw, const float* __restrict__ bw,
          float* __restrict__ outF, u16* __restrict__ outB) {
    int wave = threadIdx.x >> 6, lane = threadIdx.x & 63;
    size_t row = (size_t)blockIdx.x * 4 + wave;
    size_t off = row * E_DIM + lane * 8;
    u16x8 rv = *(const u16x8*)(resid + off);
    f4v a, b;
#pragma unroll
    for (int i = 0; i < 4; ++i) { a[i] = b2f(rv[i]); b[i] = b2f(rv[i + 4]); }
    a += *(const f4v*)(bias + lane * 8);
    b += *(const f4v*)(bias + lane * 8 + 4);
    const u16* ps[4] = {p0, p1, p2, p3};
#pragma unroll
    for (int z = 0; z < NP; ++z) {
        u16x8 t = *(const u16x8*)(ps[z] + off);
#pragma unroll
        for (int i = 0; i < 4; ++i) { a[i] += b2f(t[i]); b[i] += b2f(t[i + 4]); }
    }
    float s = (a[0] + a[1]) + (a[2] + a[3]) + (b[0] + b[1]) + (b[2] + b[3]);
#pragma unroll
    for (int o = 1; o < 64; o <<= 1) s += __shfl_xor(s, o, 64);
    float mu = s * (1.0f / E_DIM);
    float q = 0.f;
#pragma unroll
    for (int i = 0; i < 4; ++i) { float d = a[i] - mu; q += d * d; }
#pragma unroll
    for (int i = 0; i < 4; ++i) { float d = b[i] - mu; q += d * d; }
#pragma unroll
    for (int o = 1; o < 64; o <<= 1) q += __shfl_xor(q, o, 64);
    float rstd = rsqrtf(q * (1.0f / E_DIM) + 1e-5f);
    f4v g0 = *(const f4v*)(gw + lane * 8), g1 = *(const f4v*)(gw + lane * 8 + 4);
    f4v w0 = *(const f4v*)(bw + lane * 8), w1 = *(const f4v*)(bw + lane * 8 + 4);
    f4v y0, y1;
#pragma unroll
    for (int i = 0; i < 4; ++i) { y0[i] = (a[i] - mu) * rstd * g0[i] + w0[i];
                                  y1[i] = (b[i] - mu) * rstd * g1[i] + w1[i]; }
    if (WRITEF) {
        *(f4v*)(outF + off)     = y0;
        *(f4v*)(outF + off + 4) = y1;
    }
    if (WRITEB) {
        u16x8 o;
#pragma unroll
        for (int i = 0; i < 4; ++i) { o[i] = f2b(y0[i]); o[i + 4] = f2b(y1[i]); }
        *(u16x8*)(outB + off) = o;
    }
}

// ---------------------------------------------------------------- V transpose [b][h][l][d] -> [b][h][d][l]
__global__ __launch_bounds__(256) void transpose_v_k(const u16* __restrict__ vb,
                                                     u16* __restrict__ vt) {
    __shared__ __align__(16) u16 T[64 * 66];
    int t = threadIdx.x;
    int lt = blockIdx.x, bh = blockIdx.y;
    const u16* src = vb + (size_t)bh * (L_SEQ * HD) + (size_t)lt * 64 * HD;
    int lr = t >> 2, d0 = (t & 3) * 16;
    s8v va = *(const s8v*)(src + lr * HD + d0);
    s8v vb8 = *(const s8v*)(src + lr * HD + d0 + 8);
#pragma unroll
    for (int c = 0; c < 4; ++c) {
        u16x2 p0; p0[0] = (u16)va[c * 2]; p0[1] = (u16)va[c * 2 + 1];
        u16x2 p1; p1[0] = (u16)vb8[c * 2]; p1[1] = (u16)vb8[c * 2 + 1];
        *(u16x2*)(&T[lr * 66 + d0 + c * 2])     = p0;
        *(u16x2*)(&T[lr * 66 + d0 + 8 + c * 2]) = p1;
    }
    __syncthreads();
    int d = t >> 2, l0 = (t & 3) * 16;
    u16 tmp[16];
#pragma unroll
    for (int i = 0; i < 16; ++i) tmp[i] = T[(l0 + i) * 66 + d];
    u16* dst = vt + (size_t)bh * (L_SEQ * HD) + (size_t)d * L_SEQ + lt * 64 + l0;
    u16x8 o0, o1;
#pragma unroll
    for (int i = 0; i < 8; ++i) { o0[i] = tmp[i]; o1[i] = tmp[8 + i]; }
    *(u16x8*)dst       = o0;
    *(u16x8*)(dst + 8) = o1;
}

// ---------------------------------------------------------------- K-split partial GEMM BK32 dbuf + XCD swizzle (R14)
__global__ __launch_bounds__(256, 4)
void gemm_ks(const u16* __restrict__ A, const u16* __restrict__ Bw,
             int N, int K, int Kper,
             u16* __restrict__ q0, u16* __restrict__ q1) {
    __shared__ __align__(16) u16 As[2][128 * 32];
    __shared__ __align__(16) u16 Bs[2][128 * 32];
    const int tid = threadIdx.x;
    const int wave = tid >> 6, lane = tid & 63;
    const int col = lane & 15, quad = lane >> 4;
    const int n = blockIdx.x;
    const int xcd = n & 7, loc = n >> 3;             // loc in [0,64)
    const int bn = (loc & 3) * 128;
    const int bm = (xcd * 8 + ((loc >> 2) & 7)) * 128;
    const int kz = loc >> 5;
    u16* pz = kz ? q1 : q0;
    const int wm = (wave >> 1) * 64, wn = (wave & 1) * 64;
    f4v acc[4][4] = {};
    const int srow = wave * 16 + (lane >> 2);
    const int soff = (lane & 3) * 8;
    const u16* Ag = A + (size_t)(bm + srow) * K + kz * Kper + soff;
    const u16* Bg = Bw + (size_t)(bn + srow) * K + kz * Kper + soff;
    const int wo = wave * 512;
    gload_lds16(Ag,                  &As[0][wo]);
    gload_lds16(Ag + (size_t)64 * K, &As[0][wo + 2048]);
    gload_lds16(Bg,                  &Bs[0][wo]);
    gload_lds16(Bg + (size_t)64 * K, &Bs[0][wo + 2048]);
    const int nit = Kper >> 5;
    for (int t = 0; t < nit; ++t) {
        const int cur = t & 1, nxt = cur ^ 1;
        __syncthreads();
        if (t + 1 < nit) {
            const int kc = (t + 1) * 32;
            gload_lds16(Ag + kc,                  &As[nxt][wo]);
            gload_lds16(Ag + (size_t)64 * K + kc, &As[nxt][wo + 2048]);
            gload_lds16(Bg + kc,                  &Bs[nxt][wo]);
            gload_lds16(Bg + (size_t)64 * K + kc, &Bs[nxt][wo + 2048]);
        }
        s8v af[4], bf[4];
#pragma unroll
        for (int i = 0; i < 4; ++i) af[i] = *(const s8v*)(&As[cur][(wm + i * 16 + col) * 32 + quad * 8]);
#pragma unroll
        for (int j = 0; j < 4; ++j) bf[j] = *(const s8v*)(&Bs[cur][(wn + j * 16 + col) * 32 + quad * 8]);
#pragma unroll
        for (int i = 0; i < 4; ++i)
#pragma unroll
            for (int j = 0; j < 4; ++j)
                acc[i][j] = __builtin_amdgcn_mfma_f32_16x16x32_bf16(af[i], bf[j], acc[i][j], 0, 0, 0);
    }
#pragma unroll
    for (int j = 0; j < 4; ++j) {
        int gn = bn + wn + j * 16 + col;
#pragma unroll
        for (int i = 0; i < 4; ++i) {
            int m0 = bm + wm + i * 16 + quad * 4;
#pragma unroll
            for (int r = 0; r < 4; ++r)
                pz[(size_t)(m0 + r) * N + gn] = f2b(acc[i][j][r]);
        }
    }
}

// ---------------------------------------------------------------- GEMM 256x256 BK32, 8 waves, 3-deep LDS ring,
// counted vmcnt, chunk XOR swizzle, setprio. K = 512 fixed (16 tiles). Grid = 8*MT_PER_XCD*NTL (XCD-chunked).
// MODE 0: QKV scatter (Q pre-scaled). MODE 2: bias+GELU->bf16.
#define G8_STAGE(Ad, Bd, kf)                                                           \
    {                                                                                  \
        _Pragma("unroll")                                                              \
        for (int s = 0; s < 2; ++s) {                                                  \
            const int q = (s * 8 + wave) * 64 + lane;                                  \
            const int rho = q >> 2;                                                    \
            gload_lds16(A  + (size_t)(bm + rho) * Ka + (kf) + gsw, (Ad) + q * 8);      \
            gload_lds16(Bw + (size_t)(bn + rho) * Kb + (kf) + gsw, (Bd) + q * 8);      \
        }                                                                              \
    }

#define G8_COMPUTE(Ab_, Bb_)                                                           \
    {                                                                                  \
        s8v bfr[4];                                                                    \
        _Pragma("unroll")                                                              \
        for (int j = 0; j < 4; ++j) {                                                  \
            const int rB = wc * 64 + j * 16 + col;                                     \
            bfr[j] = *(const s8v*)((Bb_) + rB * 32 + ((quad ^ ((rB >> 1) & 3)) * 8));  \
        }                                                                              \
        _Pragma("unroll")                                                              \
        for (int ih = 0; ih < 2; ++ih) {                                               \
            s8v afr[4];                                                                \
            _Pragma("unroll")                                                          \
            for (int i = 0; i < 4; ++i) {                                              \
                const int rA = wr * 128 + (ih * 4 + i) * 16 + col;                     \
                afr[i] = *(const s8v*)((Ab_) + rA * 32 + ((quad ^ ((rA >> 1) & 3)) * 8)); \
            }                                                                          \
            __builtin_amdgcn_s_setprio(1);                                             \
            _Pragma("unroll")                                                          \
            for (int i = 0; i < 4; ++i)                                                \
                _Pragma("unroll")                                                      \
                for (int j = 0; j < 4; ++j)                                            \
                    acc[ih * 4 + i][j] = __builtin_amdgcn_mfma_f32_16x16x32_bf16(afr[i], bfr[j], acc[ih * 4 + i][j], 0, 0, 0); \
            __builtin_amdgcn_s_setprio(0);                                             \
        }                                                                              \
    }

template <int MODE, int NTL>
__global__ __launch_bounds__(512, 2)
void gemm8(const u16* __restrict__ A, const u16* __restrict__ Bw,
           const float* __restrict__ bias, int Ka, int Kb, int N,
           u16* __restrict__ o0, u16* __restrict__ o1, u16* __restrict__ o2) {
    extern __shared__ __align__(16) u16 LDS[];       // 3 x (A 8192 + B 8192) u16 = 96 KB
    const int tid = threadIdx.x;
    const int wave = tid >> 6, lane = tid & 63;
    const int col = lane & 15, quad = lane >> 4;
    const int wr = wave >> 2, wc = wave & 3;
    const int n = blockIdx.x;
    const int xcd = n & 7, loc = n >> 3;
    const int mt = xcd * 4 + (loc & 3);
    const int nt = loc >> 2;                         // [0, NTL)
    const int bm = mt * 256, bn = nt * 256;
    const int gsw = ((lane & 3) ^ ((lane >> 3) & 3)) * 8;
    f4v acc[8][4] = {};
    u16* A0 = LDS;          u16* B0 = LDS + 8192;
    u16* A1 = LDS + 16384;  u16* B1 = LDS + 24576;
    u16* A2 = LDS + 32768;  u16* B2 = LDS + 40960;
    G8_STAGE(A0, B0, 0);
    G8_STAGE(A1, B1, 32);
    asm volatile("s_waitcnt vmcnt(4)" ::: "memory");
    __builtin_amdgcn_s_barrier();
    __builtin_amdgcn_sched_barrier(0);
    for (int t = 0; t < 14; ++t) {
        G8_STAGE(A2, B2, (t + 2) * 32);
        G8_COMPUTE(A0, B0);
        asm volatile("s_waitcnt vmcnt(4)" ::: "memory");
        __builtin_amdgcn_s_barrier();
        __builtin_amdgcn_sched_barrier(0);
        u16* ta = A0; A0 = A1; A1 = A2; A2 = ta;
        u16* tb = B0; B0 = B1; B1 = B2; B2 = tb;
    }
    G8_COMPUTE(A0, B0);                               // tile 14
    asm volatile("s_waitcnt vmcnt(0)" ::: "memory");
    __builtin_amdgcn_s_barrier();
    __builtin_amdgcn_sched_barrier(0);
    G8_COMPUTE(A1, B1);                               // tile 15
#pragma unroll
    for (int j = 0; j < 4; ++j) {
        const int gn = bn + wc * 64 + j * 16 + col;
        const float bv = bias[gn];
        if (MODE == 0) {
            const int which = gn >> 9, hh = (gn >> 6) & 7, d = gn & 63;
            u16* dst = (which == 0) ? o0 : (which == 1) ? o1 : o2;
            const float qs = (which == 0) ? QSCALE : 1.0f;
#pragma unroll
            for (int i = 0; i < 8; ++i) {
                const int m0 = bm + wr * 128 + i * 16 + quad * 4;
#pragma unroll
                for (int r = 0; r < 4; ++r) {
                    const int m = m0 + r;
                    const int l = m >> 2, bb = m & 3;
                    dst[((size_t)(bb * H_CNT + hh) * L_SEQ + l) * HD + d] = f2b((acc[i][j][r] + bv) * qs);
                }
            }
        } else {
#pragma unroll
            for (int i = 0; i < 8; ++i) {
                const int m0 = bm + wr * 128 + i * 16 + quad * 4;
#pragma unroll
                for (int r = 0; r < 4; ++r)
                    o0[(size_t)(m0 + r) * N + gn] = f2b(gelu_f(acc[i][j][r] + bv));
            }
        }
    }
}

// ---------------------------------------------------------------- flash attention v13 (proven R8):
// 8-wave blocks = 2 kv-groups x 4 waves; group 1 dumps fp32 partials into its dead K/V LDS; group 0 combines.
__global__ __launch_bounds__(512, 4)
void attn_k(const u16* __restrict__ qg, const u16* __restrict__ kg,
            const u16* __restrict__ vtg, u16* __restrict__ og) {
    __shared__ __align__(16) u16 KV[2][2][2][2][64 * 32];   // [group][K/V][dbuf][h][.] = 64 KB
    __shared__ float LSB[2][256];                           // l partials, 2 KB
    const int tid = threadIdx.x;
    const int wave = tid >> 6, lane = tid & 63;
    const int grp = wave >> 2, w4 = wave & 3;
    const int col = lane & 15, quad = lane >> 4;
    const int flat = blockIdx.x;
    const int xcd = flat & 7, loc = flat >> 3;       // loc in [0,64)
    const int bh = xcd * 4 + (loc >> 4);             // 4 heads per XCD
    const int qc = loc & 15;
    const size_t base = (size_t)bh * (L_SEQ * HD);
    s8v qf[2][2];
#pragma unroll
    for (int t = 0; t < 2; ++t) {
        const int qrow = qc * 128 + w4 * 32 + t * 16 + col;
#pragma unroll
        for (int hh = 0; hh < 2; ++hh)
            qf[t][hh] = *(const s8v*)(qg + base + (size_t)qrow * HD + hh * 32 + quad * 8);
    }
    f4v oa[2][4] = {};
    float ls0 = 0.f, ls1 = 0.f;
    const int h = w4 & 1, r0 = (w4 >> 1) * 16;
    const int srow = lane >> 2, c = lane & 3;
    const int cp = c ^ ((srow >> 1) & 3);            // XOR-swizzled 16B chunk fetch
    // sigma row permutation: LDS row rho holds K-row 32*(rho>>5)+8*((rho>>2)&3)+4*((rho>>4)&1)+(rho&3)
    const int sig = ((srow >> 2) << 3) + ((r0 >> 4) << 2) + (srow & 3);
    const u16* Kg = kg + base + (size_t)(sig + grp * 1024) * HD + h * 32 + cp * 8;
    const u16* Vg = vtg + base + (size_t)(r0 + srow) * L_SEQ + grp * 1024 + h * 32 + cp * 8;
    {
        gload_lds16(Kg,                      &KV[grp][0][0][h][r0 * 32]);
        gload_lds16(Kg + (size_t)32 * HD,    &KV[grp][0][0][h][(r0 + 32) * 32]);
        gload_lds16(Vg,                      &KV[grp][1][0][h][r0 * 32]);
        gload_lds16(Vg + (size_t)32 * L_SEQ, &KV[grp][1][0][h][(r0 + 32) * 32]);
    }
    const int perm = (col >> 1) & 3;
    for (int it = 0; it < 16; ++it) {
        const int cur = it & 1, nxt = cur ^ 1;
        __syncthreads();
        if (it + 1 < 16) {
            const int kv0 = (it + 1) * 64;
            gload_lds16(Kg + (size_t)kv0 * HD,         &KV[grp][0][nxt][h][r0 * 32]);
            gload_lds16(Kg + (size_t)(kv0 + 32) * HD,  &KV[grp][0][nxt][h][(r0 + 32) * 32]);
            gload_lds16(Vg + kv0,                      &KV[grp][1][nxt][h][r0 * 32]);
            gload_lds16(Vg + kv0 + (size_t)32 * L_SEQ, &KV[grp][1][nxt][h][(r0 + 32) * 32]);
        }
        f4v st[2][4];
#pragma unroll
        for (int j = 0; j < 4; ++j) {
            s8v k0 = *(const s8v*)(&KV[grp][0][cur][0][(j * 16 + col) * 32 + ((quad ^ perm) * 8)]);
            s8v k1 = *(const s8v*)(&KV[grp][0][cur][1][(j * 16 + col) * 32 + ((quad ^ perm) * 8)]);
#pragma unroll
            for (int t = 0; t < 2; ++t) {
                f4v z = {};
                z = __builtin_amdgcn_mfma_f32_16x16x32_bf16(k0, qf[t][0], z, 0, 0, 0);
                z = __builtin_amdgcn_mfma_f32_16x16x32_bf16(k1, qf[t][1], z, 0, 0, 0);
                st[t][j] = z;
            }
        }
        u32 pk[2][4][2];
#pragma unroll
        for (int t = 0; t < 2; ++t)
#pragma unroll
            for (int j = 0; j < 4; ++j) {
                f4v p;
#pragma unroll
                for (int r = 0; r < 4; ++r) p[r] = __builtin_amdgcn_exp2f(st[t][j][r]);
                float psum = (p[0] + p[1]) + (p[2] + p[3]);
                if (t == 0) ls0 += psum; else ls1 += psum;
                pk[t][j][0] = pk_trunc(p[0], p[1]);
                pk[t][j][1] = pk_trunc(p[2], p[3]);
            }
#pragma unroll
        for (int c2 = 0; c2 < 2; ++c2) {
            s8v pf[2];
#pragma unroll
            for (int t = 0; t < 2; ++t) {
                u32x4 q4 = {pk[t][2 * c2][0], pk[t][2 * c2][1],
                            pk[t][2 * c2 + 1][0], pk[t][2 * c2 + 1][1]};
                pf[t] = __builtin_bit_cast(s8v, q4);
            }
#pragma unroll
            for (int dj = 0; dj < 4; ++dj) {
                s8v vf = *(const s8v*)(&KV[grp][1][cur][c2][(dj * 16 + col) * 32 + ((quad ^ perm) * 8)]);
#pragma unroll
                for (int t = 0; t < 2; ++t)
                    oa[t][dj] = __builtin_amdgcn_mfma_f32_16x16x32_bf16(pf[t], vf, oa[t][dj], 0, 0, 0);
            }
        }
    }
    // reduce l over quads within each group (lanes sharing col)
    ls0 += __shfl_xor(ls0, 16, 64); ls0 += __shfl_xor(ls0, 32, 64);
    ls1 += __shfl_xor(ls1, 16, 64); ls1 += __shfl_xor(ls1, 32, 64);
    // cross-group combine via group-1's (dead) K/V LDS region (exactly 32 KB)
    float* cmb = (float*)&KV[1][0][0][0][0];
    const int slot = w4 * 64 + lane;
    if (grp == 1) {
#pragma unroll
        for (int t = 0; t < 2; ++t)
#pragma unroll
            for (int dj = 0; dj < 4; ++dj)
                *(f4v*)(cmb + ((size_t)(t * 4 + dj) * 256 + slot) * 4) = oa[t][dj];
        LSB[0][slot] = ls0;
        LSB[1][slot] = ls1;
    }
    __syncthreads();
    if (grp == 0) {
#pragma unroll
        for (int t = 0; t < 2; ++t)
#pragma unroll
            for (int dj = 0; dj < 4; ++dj)
                oa[t][dj] += *(const f4v*)(cmb + ((size_t)(t * 4 + dj) * 256 + slot) * 4);
        ls0 += LSB[0][slot];
        ls1 += LSB[1][slot];
        const int b = bh >> 3, hd = bh & 7;
#pragma unroll
        for (int t = 0; t < 2; ++t)
#pragma unroll
            for (int r = 0; r < 4; ++r) {
                float lv = __shfl(t == 0 ? ls0 : ls1, quad * 4 + r, 64);
                float inv = frcp(lv);
                int lrow = qc * 128 + w4 * 32 + t * 16 + quad * 4 + r;
                size_t mrow = (size_t)(lrow * 4 + b) * E_DIM + hd * HD;
#pragma unroll
                for (int dj = 0; dj < 4; ++dj)
                    og[mrow + dj * 16 + col] = f2b(oa[t][dj][r] * inv);
            }
    }
}

// ---------------------------------------------------------------- host
extern "C" void kernel_launch(void* const* d_in, const int* in_sizes, int n_in,
                              void* d_out, int out_size, void* d_ws, size_t ws_size,
                              hipStream_t stream) {
    const float* x     = (const float*)d_in[0];
    const float* w_qkv = (const float*)d_in[1];
    const float* b_qkv = (const float*)d_in[2];
    const float* w_out = (const float*)d_in[3];
    const float* b_out = (const float*)d_in[4];
    const float* w1    = (const float*)d_in[5];
    const float* b1    = (const float*)d_in[6];
    const float* w2    = (const float*)d_in[7];
    const float* b2    = (const float*)d_in[8];
    const float* ln_g  = (const float*)d_in[9];
    const float* ln_b  = (const float*)d_in[10];

    char* ws = (char*)d_ws;
    u16*   WQKV = (u16*)(ws + 0);                    // 1.5 MB
    u16*   WOUT = (u16*)(ws + 1572864);              // 0.5 MB
    u16*   W1B  = (u16*)(ws + 2097152);              // 2 MB
    u16*   W2B  = (u16*)(ws + 4194304);              // 2 MB
    u16*   XPB  = (u16*)(ws + 6291456);              // 8 MB  x+pe bf16 (resid 1)
    u16*   QB   = (u16*)(ws + 14680064);             // 8 MB
    u16*   KB   = (u16*)(ws + 23068672);             // 8 MB
    u16*   VB   = (u16*)(ws + 31457280);             // 8 MB
    u16*   VT   = (u16*)(ws + 39845888);             // 8 MB
    float* PET  = (float*)(ws + 82837504);           // 8 KB PE table
    // aliases (disjoint lifetimes):
    u16*   OB   = VB;                                // attn out (VB free after transpose)
    u16*   OP0  = (u16*)(ws + 48234496);             // out-proj partials
    u16*   OP1  = (u16*)(ws + 56623104);
    u16*   X3B  = QB;                                // LN1 out bf16 (QB free after attn; resid 2)
    u16*   HB   = (u16*)(ws + 48234496);             // FFN1 out 32MB (over OPx, free after ln_c)
    u16*   FP0  = XPB;                               // FFN2 partials (free by FFN2)
    u16*   FP1  = KB;

    static bool attr_done = false;
    if (!attr_done) {
        hipFuncSetAttribute((const void*)gemm8<0, 6>,
                            hipFuncAttributeMaxDynamicSharedMemorySize, 98304);
        hipFuncSetAttribute((const void*)gemm8<2, 8>,
                            hipFuncAttributeMaxDynamicSharedMemorySize, 98304);
        attr_done = true;
    }

    pe_tab_k<<<8, 256, 0, stream>>>(PET);
    pe_add_k<<<4096, 256, 0, stream>>>(x, PET, XPB);
    conv4_k<<<3072, 256, 0, stream>>>(w_qkv, WQKV, 3 * E_DIM * E_DIM,
                                      w_out, WOUT, E_DIM * E_DIM,
                                      w1, W1B, HID * E_DIM,
                                      w2, W2B);
    gemm8<0, 6><<<192, 512, 98304, stream>>>(XPB, WQKV, b_qkv, E_DIM, E_DIM, 0,
                                             QB, KB, VB);
    transpose_v_k<<<dim3(32, 32), 256, 0, stream>>>(VB, VT);
    attn_k<<<512, 512, 0, stream>>>(QB, KB, VT, OB);
    gemm_ks<<<512, 256, 0, stream>>>(OB, WOUT, E_DIM, E_DIM, 256, OP0, OP1);
    ln_c<2, false, true><<<2048, 256, 0, stream>>>(OP0, OP1, nullptr, nullptr,
                                                   b_out, XPB, ln_g, ln_b, nullptr, X3B);
    gemm8<2, 8><<<256, 512, 98304, stream>>>(X3B, W1B, b1, E_DIM, E_DIM, HID,
                                             HB, nullptr, nullptr);
    gemm_ks<<<512, 256, 0, stream>>>(HB, W2B, E_DIM, HID, 1024, FP0, FP1);
    ln_c<2, true, false><<<2048, 256, 0, stream>>>(FP0, FP1, nullptr, nullptr,
                                                   b2, X3B, ln_g, ln_b, (float*)d_out, nullptr);
}

// Round 10
// 232.586 us; speedup vs baseline: 1.0728x; 1.0288x over previous
//
#include <hip/hip_runtime.h>

typedef unsigned short u16;
typedef unsigned int   u32;
typedef u16  u16x2 __attribute__((ext_vector_type(2)));
typedef u16  u16x4 __attribute__((ext_vector_type(4)));
typedef u16  u16x8 __attribute__((ext_vector_type(8)));
typedef short s8v  __attribute__((ext_vector_type(8)));   // 8 bf16, MFMA A/B frag (K=32 shapes)
typedef float f4v  __attribute__((ext_vector_type(4)));   // MFMA C/D frag
typedef u32  u32x2 __attribute__((ext_vector_type(2)));
typedef u32  u32x4 __attribute__((ext_vector_type(4)));

#define L_SEQ 2048
#define B_SZ  4
#define E_DIM 512
#define H_CNT 8
#define HD    64
#define HID   2048
#define M_ROWS (L_SEQ * B_SZ)   // 8192
#define QSCALE 0.18033688011112042f   // 0.125 * log2(e)

__device__ __forceinline__ u16 f2b(float f) {
    unsigned u = __builtin_bit_cast(unsigned, f);
    u += 0x7fffu + ((u >> 16) & 1u);               // RNE
    return (u16)(u >> 16);
}
__device__ __forceinline__ float b2f(u16 u) {
    u32 x = ((u32)u) << 16; return __builtin_bit_cast(float, x);
}
#if defined(__has_builtin)
#if __has_builtin(__builtin_amdgcn_cvt_pk_bf16_f32)
#define HAVE_PK_BF16 1
#endif
#if __has_builtin(__builtin_amdgcn_rcpf)
#define HAVE_RCPF 1
#endif
#endif
__device__ __forceinline__ u32 pk_trunc(float a, float b) {
#ifdef HAVE_PK_BF16
    typedef __bf16 bf2 __attribute__((ext_vector_type(2)));
    bf2 r = __builtin_amdgcn_cvt_pk_bf16_f32(a, b);
    return __builtin_bit_cast(u32, r);
#else
    u32 ua = __builtin_bit_cast(u32, a), ub = __builtin_bit_cast(u32, b);
    return (ua >> 16) | (ub & 0xffff0000u);
#endif
}
__device__ __forceinline__ float frcp(float x) {
#ifdef HAVE_RCPF
    return __builtin_amdgcn_rcpf(x);
#else
    return 1.0f / x;
#endif
}
__device__ __forceinline__ void gload_lds16(const u16* g, u16* l) {
    __builtin_amdgcn_global_load_lds((__attribute__((address_space(1))) void*)(u16*)g,
                                     (__attribute__((address_space(3))) void*)l, 16, 0, 0);
}
// tanh-GELU in sigmoid form (|err| < 1e-3, below bf16 rounding of the result)
__device__ __forceinline__ float gelu_f(float v) {
    float y2 = v * (1.5957691216f + 0.0713548576f * v * v);
    return v / (1.0f + __expf(-y2));
}

// ---------------------------------------------------------------- PE table (b,e) -> 2048 floats
__global__ __launch_bounds__(256) void pe_tab_k(float* __restrict__ pet) {
    int i = blockIdx.x * 256 + threadIdx.x;          // 2048
    int e = i & (E_DIM - 1);
    float t = (float)(i >> 9) + 1.0f;
    int ee = (e & 1) ? (e + 1) : e;
    float w = exp2f((-(float)ee / 512.0f) * 13.287712379549449f);
    pet[i] = (e & 1) ? cosf(t * w) : sinf(t * w);
}

__global__ __launch_bounds__(256) void pe_add_k(const float* __restrict__ x,
                                                const float* __restrict__ pet,
                                                u16* __restrict__ xpb) {
    int idx = (blockIdx.x * 256 + threadIdx.x) * 4;
    f4v v = *(const f4v*)(x + idx);
    f4v p = *(const f4v*)(pet + (idx & 2047));
    u16x4 o;
#pragma unroll
    for (int i = 0; i < 4; ++i) o[i] = f2b(v[i] + p[i]);
    *(u16x4*)(xpb + idx) = o;
}

__global__ __launch_bounds__(256) void conv4_k(const float* __restrict__ s1, u16* __restrict__ d1, int n1,
                                               const float* __restrict__ s2, u16* __restrict__ d2, int n2,
                                               const float* __restrict__ s3, u16* __restrict__ d3, int n3,
                                               const float* __restrict__ s4, u16* __restrict__ d4) {
    int o = (blockIdx.x * 256 + threadIdx.x) * 4;
    const float* s; u16* d;
    if (o < n1) { s = s1; d = d1; }
    else { o -= n1;
        if (o < n2) { s = s2; d = d2; }
        else { o -= n2;
            if (o < n3) { s = s3; d = d3; }
            else { o -= n3; s = s4; d = d4; } } }
    f4v v = *(const f4v*)(s + o);
    u16x4 q;
#pragma unroll
    for (int i = 0; i < 4; ++i) q[i] = f2b(v[i]);
    *(u16x4*)(d + o) = q;
}

// ---------------------------------------------------------------- LN combine (wave per row)
template <int NP, bool WRITEF, bool WRITEB>
__global__ __launch_bounds__(256)
void ln_c(const u16* __restrict__ p0, const u16* __restrict__ p1,
          const u16* __restrict__ p2, const u16* __restrict__ p3,
          const float* __restrict__ bias, const u16* __restrict__ resid,
          const float* __restrict__ gw, const float* __restrict__ bw,
          float* __restrict__ outF, u16* __restrict__ outB) {
    int wave = threadIdx.x >> 6, lane = threadIdx.x & 63;
    size_t row = (size_t)blockIdx.x * 4 + wave;
    size_t off = row * E_DIM + lane * 8;
    u16x8 rv = *(const u16x8*)(resid + off);
    f4v a, b;
#pragma unroll
    for (int i = 0; i < 4; ++i) { a[i] = b2f(rv[i]); b[i] = b2f(rv[i + 4]); }
    a += *(const f4v*)(bias + lane * 8);
    b += *(const f4v*)(bias + lane * 8 + 4);
    const u16* ps[4] = {p0, p1, p2, p3};
#pragma unroll
    for (int z = 0; z < NP; ++z) {
        u16x8 t = *(const u16x8*)(ps[z] + off);
#pragma unroll
        for (int i = 0; i < 4; ++i) { a[i] += b2f(t[i]); b[i] += b2f(t[i + 4]); }
    }
    float s = (a[0] + a[1]) + (a[2] + a[3]) + (b[0] + b[1]) + (b[2] + b[3]);
#pragma unroll
    for (int o = 1; o < 64; o <<= 1) s += __shfl_xor(s, o, 64);
    float mu = s * (1.0f / E_DIM);
    float q = 0.f;
#pragma unroll
    for (int i = 0; i < 4; ++i) { float d = a[i] - mu; q += d * d; }
#pragma unroll
    for (int i = 0; i < 4; ++i) { float d = b[i] - mu; q += d * d; }
#pragma unroll
    for (int o = 1; o < 64; o <<= 1) q += __shfl_xor(q, o, 64);
    float rstd = rsqrtf(q * (1.0f / E_DIM) + 1e-5f);
    f4v g0 = *(const f4v*)(gw + lane * 8), g1 = *(const f4v*)(gw + lane * 8 + 4);
    f4v w0 = *(const f4v*)(bw + lane * 8), w1 = *(const f4v*)(bw + lane * 8 + 4);
    f4v y0, y1;
#pragma unroll
    for (int i = 0; i < 4; ++i) { y0[i] = (a[i] - mu) * rstd * g0[i] + w0[i];
                                  y1[i] = (b[i] - mu) * rstd * g1[i] + w1[i]; }
    if (WRITEF) {
        *(f4v*)(outF + off)     = y0;
        *(f4v*)(outF + off + 4) = y1;
    }
    if (WRITEB) {
        u16x8 o;
#pragma unroll
        for (int i = 0; i < 4; ++i) { o[i] = f2b(y0[i]); o[i + 4] = f2b(y1[i]); }
        *(u16x8*)(outB + off) = o;
    }
}

// ---------------------------------------------------------------- V transpose [b][h][l][d] -> [b][h][d][l]
__global__ __launch_bounds__(256) void transpose_v_k(const u16* __restrict__ vb,
                                                     u16* __restrict__ vt) {
    __shared__ __align__(16) u16 T[64 * 66];
    int t = threadIdx.x;
    int lt = blockIdx.x, bh = blockIdx.y;
    const u16* src = vb + (size_t)bh * (L_SEQ * HD) + (size_t)lt * 64 * HD;
    int lr = t >> 2, d0 = (t & 3) * 16;
    s8v va = *(const s8v*)(src + lr * HD + d0);
    s8v vb8 = *(const s8v*)(src + lr * HD + d0 + 8);
#pragma unroll
    for (int c = 0; c < 4; ++c) {
        u16x2 p0; p0[0] = (u16)va[c * 2]; p0[1] = (u16)va[c * 2 + 1];
        u16x2 p1; p1[0] = (u16)vb8[c * 2]; p1[1] = (u16)vb8[c * 2 + 1];
        *(u16x2*)(&T[lr * 66 + d0 + c * 2])     = p0;
        *(u16x2*)(&T[lr * 66 + d0 + 8 + c * 2]) = p1;
    }
    __syncthreads();
    int d = t >> 2, l0 = (t & 3) * 16;
    u16 tmp[16];
#pragma unroll
    for (int i = 0; i < 16; ++i) tmp[i] = T[(l0 + i) * 66 + d];
    u16* dst = vt + (size_t)bh * (L_SEQ * HD) + (size_t)d * L_SEQ + lt * 64 + l0;
    u16x8 o0, o1;
#pragma unroll
    for (int i = 0; i < 8; ++i) { o0[i] = tmp[i]; o1[i] = tmp[8 + i]; }
    *(u16x8*)dst       = o0;
    *(u16x8*)(dst + 8) = o1;
}

// ---------------------------------------------------------------- K-split partial GEMM BK32 dbuf + XCD swizzle (R14)
__global__ __launch_bounds__(256, 4)
void gemm_ks(const u16* __restrict__ A, const u16* __restrict__ Bw,
             int N, int K, int Kper,
             u16* __restrict__ q0, u16* __restrict__ q1) {
    __shared__ __align__(16) u16 As[2][128 * 32];
    __shared__ __align__(16) u16 Bs[2][128 * 32];
    const int tid = threadIdx.x;
    const int wave = tid >> 6, lane = tid & 63;
    const int col = lane & 15, quad = lane >> 4;
    const int n = blockIdx.x;
    const int xcd = n & 7, loc = n >> 3;             // loc in [0,64)
    const int bn = (loc & 3) * 128;
    const int bm = (xcd * 8 + ((loc >> 2) & 7)) * 128;
    const int kz = loc >> 5;
    u16* pz = kz ? q1 : q0;
    const int wm = (wave >> 1) * 64, wn = (wave & 1) * 64;
    f4v acc[4][4] = {};
    const int srow = wave * 16 + (lane >> 2);
    const int soff = (lane & 3) * 8;
    const u16* Ag = A + (size_t)(bm + srow) * K + kz * Kper + soff;
    const u16* Bg = Bw + (size_t)(bn + srow) * K + kz * Kper + soff;
    const int wo = wave * 512;
    gload_lds16(Ag,                  &As[0][wo]);
    gload_lds16(Ag + (size_t)64 * K, &As[0][wo + 2048]);
    gload_lds16(Bg,                  &Bs[0][wo]);
    gload_lds16(Bg + (size_t)64 * K, &Bs[0][wo + 2048]);
    const int nit = Kper >> 5;
    for (int t = 0; t < nit; ++t) {
        const int cur = t & 1, nxt = cur ^ 1;
        __syncthreads();
        if (t + 1 < nit) {
            const int kc = (t + 1) * 32;
            gload_lds16(Ag + kc,                  &As[nxt][wo]);
            gload_lds16(Ag + (size_t)64 * K + kc, &As[nxt][wo + 2048]);
            gload_lds16(Bg + kc,                  &Bs[nxt][wo]);
            gload_lds16(Bg + (size_t)64 * K + kc, &Bs[nxt][wo + 2048]);
        }
        s8v af[4], bf[4];
#pragma unroll
        for (int i = 0; i < 4; ++i) af[i] = *(const s8v*)(&As[cur][(wm + i * 16 + col) * 32 + quad * 8]);
#pragma unroll
        for (int j = 0; j < 4; ++j) bf[j] = *(const s8v*)(&Bs[cur][(wn + j * 16 + col) * 32 + quad * 8]);
#pragma unroll
        for (int i = 0; i < 4; ++i)
#pragma unroll
            for (int j = 0; j < 4; ++j)
                acc[i][j] = __builtin_amdgcn_mfma_f32_16x16x32_bf16(af[i], bf[j], acc[i][j], 0, 0, 0);
    }
#pragma unroll
    for (int j = 0; j < 4; ++j) {
        int gn = bn + wn + j * 16 + col;
#pragma unroll
        for (int i = 0; i < 4; ++i) {
            int m0 = bm + wm + i * 16 + quad * 4;
#pragma unroll
            for (int r = 0; r < 4; ++r)
                pz[(size_t)(m0 + r) * N + gn] = f2b(acc[i][j][r]);
        }
    }
}

// ---------------------------------------------------------------- GEMM 256x256 BK32, 8 waves, 3-deep LDS ring,
// counted vmcnt, chunk XOR swizzle, setprio. K = 512 fixed (16 tiles). MODE 2: bias+GELU->bf16.
#define G8_STAGE(Ad, Bd, kf)                                                           \
    {                                                                                  \
        _Pragma("unroll")                                                              \
        for (int s = 0; s < 2; ++s) {                                                  \
            const int q = (s * 8 + wave) * 64 + lane;                                  \
            const int rho = q >> 2;                                                    \
            gload_lds16(A  + (size_t)(bm + rho) * Ka + (kf) + gsw, (Ad) + q * 8);      \
            gload_lds16(Bw + (size_t)(bn + rho) * Kb + (kf) + gsw, (Bd) + q * 8);      \
        }                                                                              \
    }

#define G8_COMPUTE(Ab_, Bb_)                                                           \
    {                                                                                  \
        s8v bfr[4];                                                                    \
        _Pragma("unroll")                                                              \
        for (int j = 0; j < 4; ++j) {                                                  \
            const int rB = wc * 64 + j * 16 + col;                                     \
            bfr[j] = *(const s8v*)((Bb_) + rB * 32 + ((quad ^ ((rB >> 1) & 3)) * 8));  \
        }                                                                              \
        _Pragma("unroll")                                                              \
        for (int ih = 0; ih < 2; ++ih) {                                               \
            s8v afr[4];                                                                \
            _Pragma("unroll")                                                          \
            for (int i = 0; i < 4; ++i) {                                              \
                const int rA = wr * 128 + (ih * 4 + i) * 16 + col;                     \
                afr[i] = *(const s8v*)((Ab_) + rA * 32 + ((quad ^ ((rA >> 1) & 3)) * 8)); \
            }                                                                          \
            __builtin_amdgcn_s_setprio(1);                                             \
            _Pragma("unroll")                                                          \
            for (int i = 0; i < 4; ++i)                                                \
                _Pragma("unroll")                                                      \
                for (int j = 0; j < 4; ++j)                                            \
                    acc[ih * 4 + i][j] = __builtin_amdgcn_mfma_f32_16x16x32_bf16(afr[i], bfr[j], acc[ih * 4 + i][j], 0, 0, 0); \
            __builtin_amdgcn_s_setprio(0);                                             \
        }                                                                              \
    }

template <int MODE, int NTL>
__global__ __launch_bounds__(512, 2)
void gemm8(const u16* __restrict__ A, const u16* __restrict__ Bw,
           const float* __restrict__ bias, int Ka, int Kb, int N,
           u16* __restrict__ o0, u16* __restrict__ o1, u16* __restrict__ o2) {
    extern __shared__ __align__(16) u16 LDS[];       // 3 x (A 8192 + B 8192) u16 = 96 KB
    const int tid = threadIdx.x;
    const int wave = tid >> 6, lane = tid & 63;
    const int col = lane & 15, quad = lane >> 4;
    const int wr = wave >> 2, wc = wave & 3;
    const int n = blockIdx.x;
    const int xcd = n & 7, loc = n >> 3;
    const int mt = xcd * 4 + (loc & 3);
    const int nt = loc >> 2;                         // [0, NTL)
    const int bm = mt * 256, bn = nt * 256;
    const int gsw = ((lane & 3) ^ ((lane >> 3) & 3)) * 8;
    f4v acc[8][4] = {};
    u16* A0 = LDS;          u16* B0 = LDS + 8192;
    u16* A1 = LDS + 16384;  u16* B1 = LDS + 24576;
    u16* A2 = LDS + 32768;  u16* B2 = LDS + 40960;
    G8_STAGE(A0, B0, 0);
    G8_STAGE(A1, B1, 32);
    asm volatile("s_waitcnt vmcnt(4)" ::: "memory");
    __builtin_amdgcn_s_barrier();
    __builtin_amdgcn_sched_barrier(0);
    for (int t = 0; t < 14; ++t) {
        G8_STAGE(A2, B2, (t + 2) * 32);
        G8_COMPUTE(A0, B0);
        asm volatile("s_waitcnt vmcnt(4)" ::: "memory");
        __builtin_amdgcn_s_barrier();
        __builtin_amdgcn_sched_barrier(0);
        u16* ta = A0; A0 = A1; A1 = A2; A2 = ta;
        u16* tb = B0; B0 = B1; B1 = B2; B2 = tb;
    }
    G8_COMPUTE(A0, B0);                               // tile 14
    asm volatile("s_waitcnt vmcnt(0)" ::: "memory");
    __builtin_amdgcn_s_barrier();
    __builtin_amdgcn_sched_barrier(0);
    G8_COMPUTE(A1, B1);                               // tile 15
#pragma unroll
    for (int j = 0; j < 4; ++j) {
        const int gn = bn + wc * 64 + j * 16 + col;
        const float bv = bias[gn];
#pragma unroll
        for (int i = 0; i < 8; ++i) {
            const int m0 = bm + wr * 128 + i * 16 + quad * 4;
#pragma unroll
            for (int r = 0; r < 4; ++r)
                o0[(size_t)(m0 + r) * N + gn] = f2b(gelu_f(acc[i][j][r] + bv));
        }
    }
}

// ---------------------------------------------------------------- GEMM 256x128 BK32, 8 waves (4x2), 3-deep ring,
// counted vmcnt, chunk XOR swizzle, setprio. KTILES k-tiles per block, KZL-way K-split.
// MODE 0: QKV scatter (Q pre-scaled). MODE 3: raw bf16 partial to o[kz].
#define G28_STAGE(Ad, Bd, kf)                                                          \
    {                                                                                  \
        _Pragma("unroll")                                                              \
        for (int s = 0; s < 2; ++s) {                                                  \
            const int qa = s * 512 + tid;                                              \
            const int rhoA = qa >> 2;                                                  \
            gload_lds16(A + (size_t)(bm + rhoA) * Ka + koff + (kf) + gsw, (Ad) + qa * 8); \
        }                                                                              \
        {                                                                              \
            const int rhoB = tid >> 2;                                                 \
            gload_lds16(Bw + (size_t)(bn + rhoB) * Kb + koff + (kf) + gsw, (Bd) + tid * 8); \
        }                                                                              \
    }

#define G28_COMPUTE(Ab_, Bb_)                                                          \
    {                                                                                  \
        s8v bfr[4], afr[4];                                                            \
        _Pragma("unroll")                                                              \
        for (int j = 0; j < 4; ++j) {                                                  \
            const int rB = wc * 64 + j * 16 + col;                                     \
            bfr[j] = *(const s8v*)((Bb_) + rB * 32 + ((quad ^ ((rB >> 1) & 3)) * 8));  \
        }                                                                              \
        _Pragma("unroll")                                                              \
        for (int i = 0; i < 4; ++i) {                                                  \
            const int rA = wr * 64 + i * 16 + col;                                     \
            afr[i] = *(const s8v*)((Ab_) + rA * 32 + ((quad ^ ((rA >> 1) & 3)) * 8));  \
        }                                                                              \
        __builtin_amdgcn_s_setprio(1);                                                 \
        _Pragma("unroll")                                                              \
        for (int i = 0; i < 4; ++i)                                                    \
            _Pragma("unroll")                                                          \
            for (int j = 0; j < 4; ++j)                                                \
                acc[i][j] = __builtin_amdgcn_mfma_f32_16x16x32_bf16(afr[i], bfr[j], acc[i][j], 0, 0, 0); \
        __builtin_amdgcn_s_setprio(0);                                                 \
    }

template <int MODE, int NTL, int KZL, int KTILES>
__global__ __launch_bounds__(512, 2)
void g28(const u16* __restrict__ A, const u16* __restrict__ Bw,
         const float* __restrict__ bias, int Ka, int Kb, int N,
         u16* __restrict__ o0, u16* __restrict__ o1, u16* __restrict__ o2) {
    extern __shared__ __align__(16) u16 LDS[];       // 3 x (A 8192 + B 4096) u16 = 72 KB
    const int tid = threadIdx.x;
    const int wave = tid >> 6, lane = tid & 63;
    const int col = lane & 15, quad = lane >> 4;
    const int wr = wave >> 1, wc = wave & 1;
    const int n = blockIdx.x;
    const int xcd = n & 7, loc = n >> 3;             // loc in [0, 4*NTL*KZL)
    const int mt = xcd * 4 + (loc & 3);
    const int rest = loc >> 2;
    const int nt = (NTL == 1) ? 0 : (rest % NTL);
    const int kz = (KZL == 1) ? 0 : (rest / NTL);
    const int bm = mt * 256, bn = nt * 128;
    const int koff = kz * (KTILES * 32);
    const int gsw = ((lane & 3) ^ ((lane >> 3) & 3)) * 8;
    f4v acc[4][4] = {};
    u16* A0 = LDS;          u16* B0 = LDS + 8192;
    u16* A1 = LDS + 12288;  u16* B1 = LDS + 20480;
    u16* A2 = LDS + 24576;  u16* B2 = LDS + 32768;
    G28_STAGE(A0, B0, 0);
    G28_STAGE(A1, B1, 32);
    asm volatile("s_waitcnt vmcnt(3)" ::: "memory");
    __builtin_amdgcn_s_barrier();
    __builtin_amdgcn_sched_barrier(0);
    for (int t = 0; t < KTILES - 2; ++t) {
        G28_STAGE(A2, B2, (t + 2) * 32);
        G28_COMPUTE(A0, B0);
        asm volatile("s_waitcnt vmcnt(3)" ::: "memory");
        __builtin_amdgcn_s_barrier();
        __builtin_amdgcn_sched_barrier(0);
        u16* ta = A0; A0 = A1; A1 = A2; A2 = ta;
        u16* tb = B0; B0 = B1; B1 = B2; B2 = tb;
    }
    G28_COMPUTE(A0, B0);                              // tile KTILES-2
    asm volatile("s_waitcnt vmcnt(0)" ::: "memory");
    __builtin_amdgcn_s_barrier();
    __builtin_amdgcn_sched_barrier(0);
    G28_COMPUTE(A1, B1);                              // tile KTILES-1
#pragma unroll
    for (int j = 0; j < 4; ++j) {
        const int gn = bn + wc * 64 + j * 16 + col;
        if (MODE == 0) {
            const float bv = bias[gn];
            const int which = gn >> 9, hh = (gn >> 6) & 7, d = gn & 63;
            u16* dst = (which == 0) ? o0 : (which == 1) ? o1 : o2;
            const float qs = (which == 0) ? QSCALE : 1.0f;
#pragma unroll
            for (int i = 0; i < 4; ++i) {
                const int m0 = bm + wr * 64 + i * 16 + quad * 4;
#pragma unroll
                for (int r = 0; r < 4; ++r) {
                    const int m = m0 + r;
                    const int l = m >> 2, bb = m & 3;
                    dst[((size_t)(bb * H_CNT + hh) * L_SEQ + l) * HD + d] = f2b((acc[i][j][r] + bv) * qs);
                }
            }
        } else {
            u16* pz = (kz == 0) ? o0 : o1;
#pragma unroll
            for (int i = 0; i < 4; ++i) {
                const int m0 = bm + wr * 64 + i * 16 + quad * 4;
#pragma unroll
                for (int r = 0; r < 4; ++r)
                    pz[(size_t)(m0 + r) * N + gn] = f2b(acc[i][j][r]);
            }
        }
    }
}

// ---------------------------------------------------------------- flash attention v13 (proven R8):
// 8-wave blocks = 2 kv-groups x 4 waves; group 1 dumps fp32 partials into its dead K/V LDS; group 0 combines.
__global__ __launch_bounds__(512, 4)
void attn_k(const u16* __restrict__ qg, const u16* __restrict__ kg,
            const u16* __restrict__ vtg, u16* __restrict__ og) {
    __shared__ __align__(16) u16 KV[2][2][2][2][64 * 32];   // [group][K/V][dbuf][h][.] = 64 KB
    __shared__ float LSB[2][256];                           // l partials, 2 KB
    const int tid = threadIdx.x;
    const int wave = tid >> 6, lane = tid & 63;
    const int grp = wave >> 2, w4 = wave & 3;
    const int col = lane & 15, quad = lane >> 4;
    const int flat = blockIdx.x;
    const int xcd = flat & 7, loc = flat >> 3;       // loc in [0,64)
    const int bh = xcd * 4 + (loc >> 4);             // 4 heads per XCD
    const int qc = loc & 15;
    const size_t base = (size_t)bh * (L_SEQ * HD);
    s8v qf[2][2];
#pragma unroll
    for (int t = 0; t < 2; ++t) {
        const int qrow = qc * 128 + w4 * 32 + t * 16 + col;
#pragma unroll
        for (int hh = 0; hh < 2; ++hh)
            qf[t][hh] = *(const s8v*)(qg + base + (size_t)qrow * HD + hh * 32 + quad * 8);
    }
    f4v oa[2][4] = {};
    float ls0 = 0.f, ls1 = 0.f;
    const int h = w4 & 1, r0 = (w4 >> 1) * 16;
    const int srow = lane >> 2, c = lane & 3;
    const int cp = c ^ ((srow >> 1) & 3);            // XOR-swizzled 16B chunk fetch
    // sigma row permutation: LDS row rho holds K-row 32*(rho>>5)+8*((rho>>2)&3)+4*((rho>>4)&1)+(rho&3)
    const int sig = ((srow >> 2) << 3) + ((r0 >> 4) << 2) + (srow & 3);
    const u16* Kg = kg + base + (size_t)(sig + grp * 1024) * HD + h * 32 + cp * 8;
    const u16* Vg = vtg + base + (size_t)(r0 + srow) * L_SEQ + grp * 1024 + h * 32 + cp * 8;
    {
        gload_lds16(Kg,                      &KV[grp][0][0][h][r0 * 32]);
        gload_lds16(Kg + (size_t)32 * HD,    &KV[grp][0][0][h][(r0 + 32) * 32]);
        gload_lds16(Vg,                      &KV[grp][1][0][h][r0 * 32]);
        gload_lds16(Vg + (size_t)32 * L_SEQ, &KV[grp][1][0][h][(r0 + 32) * 32]);
    }
    const int perm = (col >> 1) & 3;
    for (int it = 0; it < 16; ++it) {
        const int cur = it & 1, nxt = cur ^ 1;
        __syncthreads();
        if (it + 1 < 16) {
            const int kv0 = (it + 1) * 64;
            gload_lds16(Kg + (size_t)kv0 * HD,         &KV[grp][0][nxt][h][r0 * 32]);
            gload_lds16(Kg + (size_t)(kv0 + 32) * HD,  &KV[grp][0][nxt][h][(r0 + 32) * 32]);
            gload_lds16(Vg + kv0,                      &KV[grp][1][nxt][h][r0 * 32]);
            gload_lds16(Vg + kv0 + (size_t)32 * L_SEQ, &KV[grp][1][nxt][h][(r0 + 32) * 32]);
        }
        f4v st[2][4];
#pragma unroll
        for (int j = 0; j < 4; ++j) {
            s8v k0 = *(const s8v*)(&KV[grp][0][cur][0][(j * 16 + col) * 32 + ((quad ^ perm) * 8)]);
            s8v k1 = *(const s8v*)(&KV[grp][0][cur][1][(j * 16 + col) * 32 + ((quad ^ perm) * 8)]);
#pragma unroll
            for (int t = 0; t < 2; ++t) {
                f4v z = {};
                z = __builtin_amdgcn_mfma_f32_16x16x32_bf16(k0, qf[t][0], z, 0, 0, 0);
                z = __builtin_amdgcn_mfma_f32_16x16x32_bf16(k1, qf[t][1], z, 0, 0, 0);
                st[t][j] = z;
            }
        }
        u32 pk[2][4][2];
#pragma unroll
        for (int t = 0; t < 2; ++t)
#pragma unroll
            for (int j = 0; j < 4; ++j) {
                f4v p;
#pragma unroll
                for (int r = 0; r < 4; ++r) p[r] = __builtin_amdgcn_exp2f(st[t][j][r]);
                float psum = (p[0] + p[1]) + (p[2] + p[3]);
                if (t == 0) ls0 += psum; else ls1 += psum;
                pk[t][j][0] = pk_trunc(p[0], p[1]);
                pk[t][j][1] = pk_trunc(p[2], p[3]);
            }
#pragma unroll
        for (int c2 = 0; c2 < 2; ++c2) {
            s8v pf[2];
#pragma unroll
            for (int t = 0; t < 2; ++t) {
                u32x4 q4 = {pk[t][2 * c2][0], pk[t][2 * c2][1],
                            pk[t][2 * c2 + 1][0], pk[t][2 * c2 + 1][1]};
                pf[t] = __builtin_bit_cast(s8v, q4);
            }
#pragma unroll
            for (int dj = 0; dj < 4; ++dj) {
                s8v vf = *(const s8v*)(&KV[grp][1][cur][c2][(dj * 16 + col) * 32 + ((quad ^ perm) * 8)]);
#pragma unroll
                for (int t = 0; t < 2; ++t)
                    oa[t][dj] = __builtin_amdgcn_mfma_f32_16x16x32_bf16(pf[t], vf, oa[t][dj], 0, 0, 0);
            }
        }
    }
    // reduce l over quads within each group (lanes sharing col)
    ls0 += __shfl_xor(ls0, 16, 64); ls0 += __shfl_xor(ls0, 32, 64);
    ls1 += __shfl_xor(ls1, 16, 64); ls1 += __shfl_xor(ls1, 32, 64);
    // cross-group combine via group-1's (dead) K/V LDS region (exactly 32 KB)
    float* cmb = (float*)&KV[1][0][0][0][0];
    const int slot = w4 * 64 + lane;
    if (grp == 1) {
#pragma unroll
        for (int t = 0; t < 2; ++t)
#pragma unroll
            for (int dj = 0; dj < 4; ++dj)
                *(f4v*)(cmb + ((size_t)(t * 4 + dj) * 256 + slot) * 4) = oa[t][dj];
        LSB[0][slot] = ls0;
        LSB[1][slot] = ls1;
    }
    __syncthreads();
    if (grp == 0) {
#pragma unroll
        for (int t = 0; t < 2; ++t)
#pragma unroll
            for (int dj = 0; dj < 4; ++dj)
                oa[t][dj] += *(const f4v*)(cmb + ((size_t)(t * 4 + dj) * 256 + slot) * 4);
        ls0 += LSB[0][slot];
        ls1 += LSB[1][slot];
        const int b = bh >> 3, hd = bh & 7;
#pragma unroll
        for (int t = 0; t < 2; ++t)
#pragma unroll
            for (int r = 0; r < 4; ++r) {
                float lv = __shfl(t == 0 ? ls0 : ls1, quad * 4 + r, 64);
                float inv = frcp(lv);
                int lrow = qc * 128 + w4 * 32 + t * 16 + quad * 4 + r;
                size_t mrow = (size_t)(lrow * 4 + b) * E_DIM + hd * HD;
#pragma unroll
                for (int dj = 0; dj < 4; ++dj)
                    og[mrow + dj * 16 + col] = f2b(oa[t][dj][r] * inv);
            }
    }
}

// ---------------------------------------------------------------- host
extern "C" void kernel_launch(void* const* d_in, const int* in_sizes, int n_in,
                              void* d_out, int out_size, void* d_ws, size_t ws_size,
                              hipStream_t stream) {
    const float* x     = (const float*)d_in[0];
    const float* w_qkv = (const float*)d_in[1];
    const float* b_qkv = (const float*)d_in[2];
    const float* w_out = (const float*)d_in[3];
    const float* b_out = (const float*)d_in[4];
    const float* w1    = (const float*)d_in[5];
    const float* b1    = (const float*)d_in[6];
    const float* w2    = (const float*)d_in[7];
    const float* b2    = (const float*)d_in[8];
    const float* ln_g  = (const float*)d_in[9];
    const float* ln_b  = (const float*)d_in[10];

    char* ws = (char*)d_ws;
    u16*   WQKV = (u16*)(ws + 0);                    // 1.5 MB
    u16*   WOUT = (u16*)(ws + 1572864);              // 0.5 MB
    u16*   W1B  = (u16*)(ws + 2097152);              // 2 MB
    u16*   W2B  = (u16*)(ws + 4194304);              // 2 MB
    u16*   XPB  = (u16*)(ws + 6291456);              // 8 MB  x+pe bf16 (resid 1)
    u16*   QB   = (u16*)(ws + 14680064);             // 8 MB
    u16*   KB   = (u16*)(ws + 23068672);             // 8 MB
    u16*   VB   = (u16*)(ws + 31457280);             // 8 MB
    u16*   VT   = (u16*)(ws + 39845888);             // 8 MB
    float* PET  = (float*)(ws + 82837504);           // 8 KB PE table
    // aliases (disjoint lifetimes):
    u16*   OB   = VB;                                // attn out (VB free after transpose)
    u16*   OP0  = (u16*)(ws + 48234496);             // out-proj partials
    u16*   OP1  = (u16*)(ws + 56623104);
    u16*   X3B  = QB;                                // LN1 out bf16 (QB free after attn; resid 2)
    u16*   HB   = (u16*)(ws + 48234496);             // FFN1 out 32MB (over OPx, free after ln_c)
    u16*   FP0  = XPB;                               // FFN2 partials (free by FFN2)
    u16*   FP1  = KB;

    static bool attr_done = false;
    if (!attr_done) {
        hipFuncSetAttribute((const void*)g28<0, 12, 1, 16>,
                            hipFuncAttributeMaxDynamicSharedMemorySize, 73728);
        hipFuncSetAttribute((const void*)g28<3, 4, 2, 32>,
                            hipFuncAttributeMaxDynamicSharedMemorySize, 73728);
        hipFuncSetAttribute((const void*)gemm8<2, 8>,
                            hipFuncAttributeMaxDynamicSharedMemorySize, 98304);
        attr_done = true;
    }

    pe_tab_k<<<8, 256, 0, stream>>>(PET);
    pe_add_k<<<4096, 256, 0, stream>>>(x, PET, XPB);
    conv4_k<<<3072, 256, 0, stream>>>(w_qkv, WQKV, 3 * E_DIM * E_DIM,
                                      w_out, WOUT, E_DIM * E_DIM,
                                      w1, W1B, HID * E_DIM,
                                      w2, W2B);
    g28<0, 12, 1, 16><<<384, 512, 73728, stream>>>(XPB, WQKV, b_qkv, E_DIM, E_DIM, 0,
                                                   QB, KB, VB);
    transpose_v_k<<<dim3(32, 32), 256, 0, stream>>>(VB, VT);
    attn_k<<<512, 512, 0, stream>>>(QB, KB, VT, OB);
    gemm_ks<<<512, 256, 0, stream>>>(OB, WOUT, E_DIM, E_DIM, 256, OP0, OP1);
    ln_c<2, false, true><<<2048, 256, 0, stream>>>(OP0, OP1, nullptr, nullptr,
                                                   b_out, XPB, ln_g, ln_b, nullptr, X3B);
    gemm8<2, 8><<<256, 512, 98304, stream>>>(X3B, W1B, b1, E_DIM, E_DIM, HID,
                                             HB, nullptr, nullptr);
    g28<3, 4, 2, 32><<<256, 512, 73728, stream>>>(HB, W2B, nullptr, HID, HID, E_DIM,
                                                  FP0, FP1, nullptr);
    ln_c<2, true, false><<<2048, 256, 0, stream>>>(FP0, FP1, nullptr, nullptr,
                                                   b2, X3B, ln_g, ln_b, (float*)d_out, nullptr);
}

// Round 11
// 230.895 us; speedup vs baseline: 1.0806x; 1.0073x over previous
//
#include <hip/hip_runtime.h>

typedef unsigned short u16;
typedef unsigned int   u32;
typedef u16  u16x2 __attribute__((ext_vector_type(2)));
typedef u16  u16x4 __attribute__((ext_vector_type(4)));
typedef u16  u16x8 __attribute__((ext_vector_type(8)));
typedef short s8v  __attribute__((ext_vector_type(8)));   // 8 bf16, MFMA A/B frag (K=32 shapes)
typedef float f4v  __attribute__((ext_vector_type(4)));   // MFMA C/D frag
typedef u32  u32x2 __attribute__((ext_vector_type(2)));
typedef u32  u32x4 __attribute__((ext_vector_type(4)));

#define L_SEQ 2048
#define B_SZ  4
#define E_DIM 512
#define H_CNT 8
#define HD    64
#define HID   2048
#define M_ROWS (L_SEQ * B_SZ)   // 8192
#define QSCALE 0.18033688011112042f   // 0.125 * log2(e)

__device__ __forceinline__ u16 f2b(float f) {
    unsigned u = __builtin_bit_cast(unsigned, f);
    u += 0x7fffu + ((u >> 16) & 1u);               // RNE
    return (u16)(u >> 16);
}
__device__ __forceinline__ float b2f(u16 u) {
    u32 x = ((u32)u) << 16; return __builtin_bit_cast(float, x);
}
#if defined(__has_builtin)
#if __has_builtin(__builtin_amdgcn_cvt_pk_bf16_f32)
#define HAVE_PK_BF16 1
#endif
#if __has_builtin(__builtin_amdgcn_rcpf)
#define HAVE_RCPF 1
#endif
#endif
__device__ __forceinline__ u32 pk_trunc(float a, float b) {
#ifdef HAVE_PK_BF16
    typedef __bf16 bf2 __attribute__((ext_vector_type(2)));
    bf2 r = __builtin_amdgcn_cvt_pk_bf16_f32(a, b);
    return __builtin_bit_cast(u32, r);
#else
    u32 ua = __builtin_bit_cast(u32, a), ub = __builtin_bit_cast(u32, b);
    return (ua >> 16) | (ub & 0xffff0000u);
#endif
}
__device__ __forceinline__ float frcp(float x) {
#ifdef HAVE_RCPF
    return __builtin_amdgcn_rcpf(x);
#else
    return 1.0f / x;
#endif
}
__device__ __forceinline__ void gload_lds16(const u16* g, u16* l) {
    __builtin_amdgcn_global_load_lds((__attribute__((address_space(1))) void*)(u16*)g,
                                     (__attribute__((address_space(3))) void*)l, 16, 0, 0);
}
// tanh-GELU in sigmoid form (|err| < 1e-3, below bf16 rounding of the result)
__device__ __forceinline__ float gelu_f(float v) {
    float y2 = v * (1.5957691216f + 0.0713548576f * v * v);
    return v / (1.0f + __expf(-y2));
}

// ---------------------------------------------------------------- PE table (b,e) -> 2048 floats
__global__ __launch_bounds__(256) void pe_tab_k(float* __restrict__ pet) {
    int i = blockIdx.x * 256 + threadIdx.x;          // 2048
    int e = i & (E_DIM - 1);
    float t = (float)(i >> 9) + 1.0f;
    int ee = (e & 1) ? (e + 1) : e;
    float w = exp2f((-(float)ee / 512.0f) * 13.287712379549449f);
    pet[i] = (e & 1) ? cosf(t * w) : sinf(t * w);
}

__global__ __launch_bounds__(256) void pe_add_k(const float* __restrict__ x,
                                                const float* __restrict__ pet,
                                                u16* __restrict__ xpb) {
    int idx = (blockIdx.x * 256 + threadIdx.x) * 4;
    f4v v = *(const f4v*)(x + idx);
    f4v p = *(const f4v*)(pet + (idx & 2047));
    u16x4 o;
#pragma unroll
    for (int i = 0; i < 4; ++i) o[i] = f2b(v[i] + p[i]);
    *(u16x4*)(xpb + idx) = o;
}

__global__ __launch_bounds__(256) void conv4_k(const float* __restrict__ s1, u16* __restrict__ d1, int n1,
                                               const float* __restrict__ s2, u16* __restrict__ d2, int n2,
                                               const float* __restrict__ s3, u16* __restrict__ d3, int n3,
                                               const float* __restrict__ s4, u16* __restrict__ d4) {
    int o = (blockIdx.x * 256 + threadIdx.x) * 4;
    const float* s; u16* d;
    if (o < n1) { s = s1; d = d1; }
    else { o -= n1;
        if (o < n2) { s = s2; d = d2; }
        else { o -= n2;
            if (o < n3) { s = s3; d = d3; }
            else { o -= n3; s = s4; d = d4; } } }
    f4v v = *(const f4v*)(s + o);
    u16x4 q;
#pragma unroll
    for (int i = 0; i < 4; ++i) q[i] = f2b(v[i]);
    *(u16x4*)(d + o) = q;
}

// ---------------------------------------------------------------- LN combine (wave per row)
template <int NP, bool WRITEF, bool WRITEB>
__global__ __launch_bounds__(256)
void ln_c(const u16* __restrict__ p0, const u16* __restrict__ p1,
          const u16* __restrict__ p2, const u16* __restrict__ p3,
          const float* __restrict__ bias, const u16* __restrict__ resid,
          const float* __restrict__ gw, const float* __restrict__ bw,
          float* __restrict__ outF, u16* __restrict__ outB) {
    int wave = threadIdx.x >> 6, lane = threadIdx.x & 63;
    size_t row = (size_t)blockIdx.x * 4 + wave;
    size_t off = row * E_DIM + lane * 8;
    u16x8 rv = *(const u16x8*)(resid + off);
    f4v a, b;
#pragma unroll
    for (int i = 0; i < 4; ++i) { a[i] = b2f(rv[i]); b[i] = b2f(rv[i + 4]); }
    a += *(const f4v*)(bias + lane * 8);
    b += *(const f4v*)(bias + lane * 8 + 4);
    const u16* ps[4] = {p0, p1, p2, p3};
#pragma unroll
    for (int z = 0; z < NP; ++z) {
        u16x8 t = *(const u16x8*)(ps[z] + off);
#pragma unroll
        for (int i = 0; i < 4; ++i) { a[i] += b2f(t[i]); b[i] += b2f(t[i + 4]); }
    }
    float s = (a[0] + a[1]) + (a[2] + a[3]) + (b[0] + b[1]) + (b[2] + b[3]);
#pragma unroll
    for (int o = 1; o < 64; o <<= 1) s += __shfl_xor(s, o, 64);
    float mu = s * (1.0f / E_DIM);
    float q = 0.f;
#pragma unroll
    for (int i = 0; i < 4; ++i) { float d = a[i] - mu; q += d * d; }
#pragma unroll
    for (int i = 0; i < 4; ++i) { float d = b[i] - mu; q += d * d; }
#pragma unroll
    for (int o = 1; o < 64; o <<= 1) q += __shfl_xor(q, o, 64);
    float rstd = rsqrtf(q * (1.0f / E_DIM) + 1e-5f);
    f4v g0 = *(const f4v*)(gw + lane * 8), g1 = *(const f4v*)(gw + lane * 8 + 4);
    f4v w0 = *(const f4v*)(bw + lane * 8), w1 = *(const f4v*)(bw + lane * 8 + 4);
    f4v y0, y1;
#pragma unroll
    for (int i = 0; i < 4; ++i) { y0[i] = (a[i] - mu) * rstd * g0[i] + w0[i];
                                  y1[i] = (b[i] - mu) * rstd * g1[i] + w1[i]; }
    if (WRITEF) {
        *(f4v*)(outF + off)     = y0;
        *(f4v*)(outF + off + 4) = y1;
    }
    if (WRITEB) {
        u16x8 o;
#pragma unroll
        for (int i = 0; i < 4; ++i) { o[i] = f2b(y0[i]); o[i + 4] = f2b(y1[i]); }
        *(u16x8*)(outB + off) = o;
    }
}

// ---------------------------------------------------------------- V transpose [b][h][l][d] -> [b][h][d][l]
__global__ __launch_bounds__(256) void transpose_v_k(const u16* __restrict__ vb,
                                                     u16* __restrict__ vt) {
    __shared__ __align__(16) u16 T[64 * 66];
    int t = threadIdx.x;
    int lt = blockIdx.x, bh = blockIdx.y;
    const u16* src = vb + (size_t)bh * (L_SEQ * HD) + (size_t)lt * 64 * HD;
    int lr = t >> 2, d0 = (t & 3) * 16;
    s8v va = *(const s8v*)(src + lr * HD + d0);
    s8v vb8 = *(const s8v*)(src + lr * HD + d0 + 8);
#pragma unroll
    for (int c = 0; c < 4; ++c) {
        u16x2 p0; p0[0] = (u16)va[c * 2]; p0[1] = (u16)va[c * 2 + 1];
        u16x2 p1; p1[0] = (u16)vb8[c * 2]; p1[1] = (u16)vb8[c * 2 + 1];
        *(u16x2*)(&T[lr * 66 + d0 + c * 2])     = p0;
        *(u16x2*)(&T[lr * 66 + d0 + 8 + c * 2]) = p1;
    }
    __syncthreads();
    int d = t >> 2, l0 = (t & 3) * 16;
    u16 tmp[16];
#pragma unroll
    for (int i = 0; i < 16; ++i) tmp[i] = T[(l0 + i) * 66 + d];
    u16* dst = vt + (size_t)bh * (L_SEQ * HD) + (size_t)d * L_SEQ + lt * 64 + l0;
    u16x8 o0, o1;
#pragma unroll
    for (int i = 0; i < 8; ++i) { o0[i] = tmp[i]; o1[i] = tmp[8 + i]; }
    *(u16x8*)dst       = o0;
    *(u16x8*)(dst + 8) = o1;
}

// ---------------------------------------------------------------- K-split partial GEMM BK32 dbuf + XCD swizzle (R14)
__global__ __launch_bounds__(256, 4)
void gemm_ks(const u16* __restrict__ A, const u16* __restrict__ Bw,
             int N, int K, int Kper,
             u16* __restrict__ q0, u16* __restrict__ q1) {
    __shared__ __align__(16) u16 As[2][128 * 32];
    __shared__ __align__(16) u16 Bs[2][128 * 32];
    const int tid = threadIdx.x;
    const int wave = tid >> 6, lane = tid & 63;
    const int col = lane & 15, quad = lane >> 4;
    const int n = blockIdx.x;
    const int xcd = n & 7, loc = n >> 3;             // loc in [0,64)
    const int bn = (loc & 3) * 128;
    const int bm = (xcd * 8 + ((loc >> 2) & 7)) * 128;
    const int kz = loc >> 5;
    u16* pz = kz ? q1 : q0;
    const int wm = (wave >> 1) * 64, wn = (wave & 1) * 64;
    f4v acc[4][4] = {};
    const int srow = wave * 16 + (lane >> 2);
    const int soff = (lane & 3) * 8;
    const u16* Ag = A + (size_t)(bm + srow) * K + kz * Kper + soff;
    const u16* Bg = Bw + (size_t)(bn + srow) * K + kz * Kper + soff;
    const int wo = wave * 512;
    gload_lds16(Ag,                  &As[0][wo]);
    gload_lds16(Ag + (size_t)64 * K, &As[0][wo + 2048]);
    gload_lds16(Bg,                  &Bs[0][wo]);
    gload_lds16(Bg + (size_t)64 * K, &Bs[0][wo + 2048]);
    const int nit = Kper >> 5;
    for (int t = 0; t < nit; ++t) {
        const int cur = t & 1, nxt = cur ^ 1;
        __syncthreads();
        if (t + 1 < nit) {
            const int kc = (t + 1) * 32;
            gload_lds16(Ag + kc,                  &As[nxt][wo]);
            gload_lds16(Ag + (size_t)64 * K + kc, &As[nxt][wo + 2048]);
            gload_lds16(Bg + kc,                  &Bs[nxt][wo]);
            gload_lds16(Bg + (size_t)64 * K + kc, &Bs[nxt][wo + 2048]);
        }
        s8v af[4], bf[4];
#pragma unroll
        for (int i = 0; i < 4; ++i) af[i] = *(const s8v*)(&As[cur][(wm + i * 16 + col) * 32 + quad * 8]);
#pragma unroll
        for (int j = 0; j < 4; ++j) bf[j] = *(const s8v*)(&Bs[cur][(wn + j * 16 + col) * 32 + quad * 8]);
#pragma unroll
        for (int i = 0; i < 4; ++i)
#pragma unroll
            for (int j = 0; j < 4; ++j)
                acc[i][j] = __builtin_amdgcn_mfma_f32_16x16x32_bf16(af[i], bf[j], acc[i][j], 0, 0, 0);
    }
#pragma unroll
    for (int j = 0; j < 4; ++j) {
        int gn = bn + wn + j * 16 + col;
#pragma unroll
        for (int i = 0; i < 4; ++i) {
            int m0 = bm + wm + i * 16 + quad * 4;
#pragma unroll
            for (int r = 0; r < 4; ++r)
                pz[(size_t)(m0 + r) * N + gn] = f2b(acc[i][j][r]);
        }
    }
}

// ---------------------------------------------------------------- GEMM 256x128 BK32, 8 waves (4x2), 3-deep ring,
// counted vmcnt, chunk XOR swizzle, setprio. KTILES k-tiles per block, KZL-way K-split.
// 72 KB LDS -> 2 blocks/CU (the co-resident partner hides barrier drains — m114 mechanism).
// MODE 0: QKV scatter (Q pre-scaled). MODE 2: bias+GELU->bf16. MODE 3: raw bf16 partial to o[kz].
#define G28_STAGE(Ad, Bd, kf)                                                          \
    {                                                                                  \
        _Pragma("unroll")                                                              \
        for (int s = 0; s < 2; ++s) {                                                  \
            const int qa = s * 512 + tid;                                              \
            const int rhoA = qa >> 2;                                                  \
            gload_lds16(A + (size_t)(bm + rhoA) * Ka + koff + (kf) + gsw, (Ad) + qa * 8); \
        }                                                                              \
        {                                                                              \
            const int rhoB = tid >> 2;                                                 \
            gload_lds16(Bw + (size_t)(bn + rhoB) * Kb + koff + (kf) + gsw, (Bd) + tid * 8); \
        }                                                                              \
    }

#define G28_COMPUTE(Ab_, Bb_)                                                          \
    {                                                                                  \
        s8v bfr[4], afr[4];                                                            \
        _Pragma("unroll")                                                              \
        for (int j = 0; j < 4; ++j) {                                                  \
            const int rB = wc * 64 + j * 16 + col;                                     \
            bfr[j] = *(const s8v*)((Bb_) + rB * 32 + ((quad ^ ((rB >> 1) & 3)) * 8));  \
        }                                                                              \
        _Pragma("unroll")                                                              \
        for (int i = 0; i < 4; ++i) {                                                  \
            const int rA = wr * 64 + i * 16 + col;                                     \
            afr[i] = *(const s8v*)((Ab_) + rA * 32 + ((quad ^ ((rA >> 1) & 3)) * 8));  \
        }                                                                              \
        __builtin_amdgcn_s_setprio(1);                                                 \
        _Pragma("unroll")                                                              \
        for (int i = 0; i < 4; ++i)                                                    \
            _Pragma("unroll")                                                          \
            for (int j = 0; j < 4; ++j)                                                \
                acc[i][j] = __builtin_amdgcn_mfma_f32_16x16x32_bf16(afr[i], bfr[j], acc[i][j], 0, 0, 0); \
        __builtin_amdgcn_s_setprio(0);                                                 \
    }

template <int MODE, int NTL, int KZL, int KTILES>
__global__ __launch_bounds__(512, 2)
void g28(const u16* __restrict__ A, const u16* __restrict__ Bw,
         const float* __restrict__ bias, int Ka, int Kb, int N,
         u16* __restrict__ o0, u16* __restrict__ o1, u16* __restrict__ o2) {
    extern __shared__ __align__(16) u16 LDS[];       // 3 x (A 8192 + B 4096) u16 = 72 KB
    const int tid = threadIdx.x;
    const int wave = tid >> 6, lane = tid & 63;
    const int col = lane & 15, quad = lane >> 4;
    const int wr = wave >> 1, wc = wave & 1;
    const int n = blockIdx.x;
    const int xcd = n & 7, loc = n >> 3;             // loc in [0, 4*NTL*KZL)
    const int mt = xcd * 4 + (loc & 3);
    const int rest = loc >> 2;
    const int nt = (NTL == 1) ? 0 : (rest % NTL);
    const int kz = (KZL == 1) ? 0 : (rest / NTL);
    const int bm = mt * 256, bn = nt * 128;
    const int koff = kz * (KTILES * 32);
    const int gsw = ((lane & 3) ^ ((lane >> 3) & 3)) * 8;
    f4v acc[4][4] = {};
    u16* A0 = LDS;          u16* B0 = LDS + 8192;
    u16* A1 = LDS + 12288;  u16* B1 = LDS + 20480;
    u16* A2 = LDS + 24576;  u16* B2 = LDS + 32768;
    G28_STAGE(A0, B0, 0);
    G28_STAGE(A1, B1, 32);
    asm volatile("s_waitcnt vmcnt(3)" ::: "memory");
    __builtin_amdgcn_s_barrier();
    __builtin_amdgcn_sched_barrier(0);
    for (int t = 0; t < KTILES - 2; ++t) {
        G28_STAGE(A2, B2, (t + 2) * 32);
        G28_COMPUTE(A0, B0);
        asm volatile("s_waitcnt vmcnt(3)" ::: "memory");
        __builtin_amdgcn_s_barrier();
        __builtin_amdgcn_sched_barrier(0);
        u16* ta = A0; A0 = A1; A1 = A2; A2 = ta;
        u16* tb = B0; B0 = B1; B1 = B2; B2 = tb;
    }
    G28_COMPUTE(A0, B0);                              // tile KTILES-2
    asm volatile("s_waitcnt vmcnt(0)" ::: "memory");
    __builtin_amdgcn_s_barrier();
    __builtin_amdgcn_sched_barrier(0);
    G28_COMPUTE(A1, B1);                              // tile KTILES-1
#pragma unroll
    for (int j = 0; j < 4; ++j) {
        const int gn = bn + wc * 64 + j * 16 + col;
        if (MODE == 0) {
            const float bv = bias[gn];
            const int which = gn >> 9, hh = (gn >> 6) & 7, d = gn & 63;
            u16* dst = (which == 0) ? o0 : (which == 1) ? o1 : o2;
            const float qs = (which == 0) ? QSCALE : 1.0f;
#pragma unroll
            for (int i = 0; i < 4; ++i) {
                const int m0 = bm + wr * 64 + i * 16 + quad * 4;
#pragma unroll
                for (int r = 0; r < 4; ++r) {
                    const int m = m0 + r;
                    const int l = m >> 2, bb = m & 3;
                    dst[((size_t)(bb * H_CNT + hh) * L_SEQ + l) * HD + d] = f2b((acc[i][j][r] + bv) * qs);
                }
            }
        } else if (MODE == 2) {
            const float bv = bias[gn];
#pragma unroll
            for (int i = 0; i < 4; ++i) {
                const int m0 = bm + wr * 64 + i * 16 + quad * 4;
#pragma unroll
                for (int r = 0; r < 4; ++r)
                    o0[(size_t)(m0 + r) * N + gn] = f2b(gelu_f(acc[i][j][r] + bv));
            }
        } else {
            u16* pz = (kz == 0) ? o0 : o1;
#pragma unroll
            for (int i = 0; i < 4; ++i) {
                const int m0 = bm + wr * 64 + i * 16 + quad * 4;
#pragma unroll
                for (int r = 0; r < 4; ++r)
                    pz[(size_t)(m0 + r) * N + gn] = f2b(acc[i][j][r]);
            }
        }
    }
}

// ---------------------------------------------------------------- flash attention v13 (proven R8):
// 8-wave blocks = 2 kv-groups x 4 waves; group 1 dumps fp32 partials into its dead K/V LDS; group 0 combines.
__global__ __launch_bounds__(512, 4)
void attn_k(const u16* __restrict__ qg, const u16* __restrict__ kg,
            const u16* __restrict__ vtg, u16* __restrict__ og) {
    __shared__ __align__(16) u16 KV[2][2][2][2][64 * 32];   // [group][K/V][dbuf][h][.] = 64 KB
    __shared__ float LSB[2][256];                           // l partials, 2 KB
    const int tid = threadIdx.x;
    const int wave = tid >> 6, lane = tid & 63;
    const int grp = wave >> 2, w4 = wave & 3;
    const int col = lane & 15, quad = lane >> 4;
    const int flat = blockIdx.x;
    const int xcd = flat & 7, loc = flat >> 3;       // loc in [0,64)
    const int bh = xcd * 4 + (loc >> 4);             // 4 heads per XCD
    const int qc = loc & 15;
    const size_t base = (size_t)bh * (L_SEQ * HD);
    s8v qf[2][2];
#pragma unroll
    for (int t = 0; t < 2; ++t) {
        const int qrow = qc * 128 + w4 * 32 + t * 16 + col;
#pragma unroll
        for (int hh = 0; hh < 2; ++hh)
            qf[t][hh] = *(const s8v*)(qg + base + (size_t)qrow * HD + hh * 32 + quad * 8);
    }
    f4v oa[2][4] = {};
    float ls0 = 0.f, ls1 = 0.f;
    const int h = w4 & 1, r0 = (w4 >> 1) * 16;
    const int srow = lane >> 2, c = lane & 3;
    const int cp = c ^ ((srow >> 1) & 3);            // XOR-swizzled 16B chunk fetch
    // sigma row permutation: LDS row rho holds K-row 32*(rho>>5)+8*((rho>>2)&3)+4*((rho>>4)&1)+(rho&3)
    const int sig = ((srow >> 2) << 3) + ((r0 >> 4) << 2) + (srow & 3);
    const u16* Kg = kg + base + (size_t)(sig + grp * 1024) * HD + h * 32 + cp * 8;
    const u16* Vg = vtg + base + (size_t)(r0 + srow) * L_SEQ + grp * 1024 + h * 32 + cp * 8;
    {
        gload_lds16(Kg,                      &KV[grp][0][0][h][r0 * 32]);
        gload_lds16(Kg + (size_t)32 * HD,    &KV[grp][0][0][h][(r0 + 32) * 32]);
        gload_lds16(Vg,                      &KV[grp][1][0][h][r0 * 32]);
        gload_lds16(Vg + (size_t)32 * L_SEQ, &KV[grp][1][0][h][(r0 + 32) * 32]);
    }
    const int perm = (col >> 1) & 3;
    for (int it = 0; it < 16; ++it) {
        const int cur = it & 1, nxt = cur ^ 1;
        __syncthreads();
        if (it + 1 < 16) {
            const int kv0 = (it + 1) * 64;
            gload_lds16(Kg + (size_t)kv0 * HD,         &KV[grp][0][nxt][h][r0 * 32]);
            gload_lds16(Kg + (size_t)(kv0 + 32) * HD,  &KV[grp][0][nxt][h][(r0 + 32) * 32]);
            gload_lds16(Vg + kv0,                      &KV[grp][1][nxt][h][r0 * 32]);
            gload_lds16(Vg + kv0 + (size_t)32 * L_SEQ, &KV[grp][1][nxt][h][(r0 + 32) * 32]);
        }
        f4v st[2][4];
#pragma unroll
        for (int j = 0; j < 4; ++j) {
            s8v k0 = *(const s8v*)(&KV[grp][0][cur][0][(j * 16 + col) * 32 + ((quad ^ perm) * 8)]);
            s8v k1 = *(const s8v*)(&KV[grp][0][cur][1][(j * 16 + col) * 32 + ((quad ^ perm) * 8)]);
#pragma unroll
            for (int t = 0; t < 2; ++t) {
                f4v z = {};
                z = __builtin_amdgcn_mfma_f32_16x16x32_bf16(k0, qf[t][0], z, 0, 0, 0);
                z = __builtin_amdgcn_mfma_f32_16x16x32_bf16(k1, qf[t][1], z, 0, 0, 0);
                st[t][j] = z;
            }
        }
        u32 pk[2][4][2];
#pragma unroll
        for (int t = 0; t < 2; ++t)
#pragma unroll
            for (int j = 0; j < 4; ++j) {
                f4v p;
#pragma unroll
                for (int r = 0; r < 4; ++r) p[r] = __builtin_amdgcn_exp2f(st[t][j][r]);
                float psum = (p[0] + p[1]) + (p[2] + p[3]);
                if (t == 0) ls0 += psum; else ls1 += psum;
                pk[t][j][0] = pk_trunc(p[0], p[1]);
                pk[t][j][1] = pk_trunc(p[2], p[3]);
            }
#pragma unroll
        for (int c2 = 0; c2 < 2; ++c2) {
            s8v pf[2];
#pragma unroll
            for (int t = 0; t < 2; ++t) {
                u32x4 q4 = {pk[t][2 * c2][0], pk[t][2 * c2][1],
                            pk[t][2 * c2 + 1][0], pk[t][2 * c2 + 1][1]};
                pf[t] = __builtin_bit_cast(s8v, q4);
            }
#pragma unroll
            for (int dj = 0; dj < 4; ++dj) {
                s8v vf = *(const s8v*)(&KV[grp][1][cur][c2][(dj * 16 + col) * 32 + ((quad ^ perm) * 8)]);
#pragma unroll
                for (int t = 0; t < 2; ++t)
                    oa[t][dj] = __builtin_amdgcn_mfma_f32_16x16x32_bf16(pf[t], vf, oa[t][dj], 0, 0, 0);
            }
        }
    }
    // reduce l over quads within each group (lanes sharing col)
    ls0 += __shfl_xor(ls0, 16, 64); ls0 += __shfl_xor(ls0, 32, 64);
    ls1 += __shfl_xor(ls1, 16, 64); ls1 += __shfl_xor(ls1, 32, 64);
    // cross-group combine via group-1's (dead) K/V LDS region (exactly 32 KB)
    float* cmb = (float*)&KV[1][0][0][0][0];
    const int slot = w4 * 64 + lane;
    if (grp == 1) {
#pragma unroll
        for (int t = 0; t < 2; ++t)
#pragma unroll
            for (int dj = 0; dj < 4; ++dj)
                *(f4v*)(cmb + ((size_t)(t * 4 + dj) * 256 + slot) * 4) = oa[t][dj];
        LSB[0][slot] = ls0;
        LSB[1][slot] = ls1;
    }
    __syncthreads();
    if (grp == 0) {
#pragma unroll
        for (int t = 0; t < 2; ++t)
#pragma unroll
            for (int dj = 0; dj < 4; ++dj)
                oa[t][dj] += *(const f4v*)(cmb + ((size_t)(t * 4 + dj) * 256 + slot) * 4);
        ls0 += LSB[0][slot];
        ls1 += LSB[1][slot];
        const int b = bh >> 3, hd = bh & 7;
#pragma unroll
        for (int t = 0; t < 2; ++t)
#pragma unroll
            for (int r = 0; r < 4; ++r) {
                float lv = __shfl(t == 0 ? ls0 : ls1, quad * 4 + r, 64);
                float inv = frcp(lv);
                int lrow = qc * 128 + w4 * 32 + t * 16 + quad * 4 + r;
                size_t mrow = (size_t)(lrow * 4 + b) * E_DIM + hd * HD;
#pragma unroll
                for (int dj = 0; dj < 4; ++dj)
                    og[mrow + dj * 16 + col] = f2b(oa[t][dj][r] * inv);
            }
    }
}

// ---------------------------------------------------------------- host
extern "C" void kernel_launch(void* const* d_in, const int* in_sizes, int n_in,
                              void* d_out, int out_size, void* d_ws, size_t ws_size,
                              hipStream_t stream) {
    const float* x     = (const float*)d_in[0];
    const float* w_qkv = (const float*)d_in[1];
    const float* b_qkv = (const float*)d_in[2];
    const float* w_out = (const float*)d_in[3];
    const float* b_out = (const float*)d_in[4];
    const float* w1    = (const float*)d_in[5];
    const float* b1    = (const float*)d_in[6];
    const float* w2    = (const float*)d_in[7];
    const float* b2    = (const float*)d_in[8];
    const float* ln_g  = (const float*)d_in[9];
    const float* ln_b  = (const float*)d_in[10];

    char* ws = (char*)d_ws;
    u16*   WQKV = (u16*)(ws + 0);                    // 1.5 MB
    u16*   WOUT = (u16*)(ws + 1572864);              // 0.5 MB
    u16*   W1B  = (u16*)(ws + 2097152);              // 2 MB
    u16*   W2B  = (u16*)(ws + 4194304);              // 2 MB
    u16*   XPB  = (u16*)(ws + 6291456);              // 8 MB  x+pe bf16 (resid 1)
    u16*   QB   = (u16*)(ws + 14680064);             // 8 MB
    u16*   KB   = (u16*)(ws + 23068672);             // 8 MB
    u16*   VB   = (u16*)(ws + 31457280);             // 8 MB
    u16*   VT   = (u16*)(ws + 39845888);             // 8 MB
    float* PET  = (float*)(ws + 82837504);           // 8 KB PE table
    // aliases (disjoint lifetimes):
    u16*   OB   = VB;                                // attn out (VB free after transpose)
    u16*   OP0  = (u16*)(ws + 48234496);             // out-proj partials
    u16*   OP1  = (u16*)(ws + 56623104);
    u16*   X3B  = QB;                                // LN1 out bf16 (QB free after attn; resid 2)
    u16*   HB   = (u16*)(ws + 48234496);             // FFN1 out 32MB (over OPx, free after ln_c)
    u16*   FP0  = XPB;                               // FFN2 partials (free by FFN2)
    u16*   FP1  = KB;

    static bool attr_done = false;
    if (!attr_done) {
        hipFuncSetAttribute((const void*)g28<0, 12, 1, 16>,
                            hipFuncAttributeMaxDynamicSharedMemorySize, 73728);
        hipFuncSetAttribute((const void*)g28<2, 16, 1, 16>,
                            hipFuncAttributeMaxDynamicSharedMemorySize, 73728);
        hipFuncSetAttribute((const void*)g28<3, 4, 2, 32>,
                            hipFuncAttributeMaxDynamicSharedMemorySize, 73728);
        attr_done = true;
    }

    pe_tab_k<<<8, 256, 0, stream>>>(PET);
    pe_add_k<<<4096, 256, 0, stream>>>(x, PET, XPB);
    conv4_k<<<3072, 256, 0, stream>>>(w_qkv, WQKV, 3 * E_DIM * E_DIM,
                                      w_out, WOUT, E_DIM * E_DIM,
                                      w1, W1B, HID * E_DIM,
                                      w2, W2B);
    g28<0, 12, 1, 16><<<384, 512, 73728, stream>>>(XPB, WQKV, b_qkv, E_DIM, E_DIM, 0,
                                                   QB, KB, VB);
    transpose_v_k<<<dim3(32, 32), 256, 0, stream>>>(VB, VT);
    attn_k<<<512, 512, 0, stream>>>(QB, KB, VT, OB);
    gemm_ks<<<512, 256, 0, stream>>>(OB, WOUT, E_DIM, E_DIM, 256, OP0, OP1);
    ln_c<2, false, true><<<2048, 256, 0, stream>>>(OP0, OP1, nullptr, nullptr,
                                                   b_out, XPB, ln_g, ln_b, nullptr, X3B);
    g28<2, 16, 1, 16><<<512, 512, 73728, stream>>>(X3B, W1B, b1, E_DIM, E_DIM, HID,
                                                   HB, nullptr, nullptr);
    g28<3, 4, 2, 32><<<256, 512, 73728, stream>>>(HB, W2B, nullptr, HID, HID, E_DIM,
                                                  FP0, FP1, nullptr);
    ln_c<2, true, false><<<2048, 256, 0, stream>>>(FP0, FP1, nullptr, nullptr,
                                                   b2, X3B, ln_g, ln_b, (float*)d_out, nullptr);
}

// Round 12
// 223.695 us; speedup vs baseline: 1.1154x; 1.0322x over previous
//
#include <hip/hip_runtime.h>

typedef unsigned short u16;
typedef unsigned int   u32;
typedef u16  u16x2 __attribute__((ext_vector_type(2)));
typedef u16  u16x4 __attribute__((ext_vector_type(4)));
typedef u16  u16x8 __attribute__((ext_vector_type(8)));
typedef short s8v  __attribute__((ext_vector_type(8)));   // 8 bf16, MFMA A/B frag (K=32 shapes)
typedef float f4v  __attribute__((ext_vector_type(4)));   // MFMA C/D frag
typedef u32  u32x2 __attribute__((ext_vector_type(2)));
typedef u32  u32x4 __attribute__((ext_vector_type(4)));

#define L_SEQ 2048
#define B_SZ  4
#define E_DIM 512
#define H_CNT 8
#define HD    64
#define HID   2048
#define M_ROWS (L_SEQ * B_SZ)   // 8192
#define QSCALE 0.18033688011112042f   // 0.125 * log2(e)

__device__ __forceinline__ u16 f2b(float f) {
    unsigned u = __builtin_bit_cast(unsigned, f);
    u += 0x7fffu + ((u >> 16) & 1u);               // RNE
    return (u16)(u >> 16);
}
__device__ __forceinline__ float b2f(u16 u) {
    u32 x = ((u32)u) << 16; return __builtin_bit_cast(float, x);
}
#if defined(__has_builtin)
#if __has_builtin(__builtin_amdgcn_cvt_pk_bf16_f32)
#define HAVE_PK_BF16 1
#endif
#if __has_builtin(__builtin_amdgcn_rcpf)
#define HAVE_RCPF 1
#endif
#endif
__device__ __forceinline__ u32 pk_trunc(float a, float b) {
#ifdef HAVE_PK_BF16
    typedef __bf16 bf2 __attribute__((ext_vector_type(2)));
    bf2 r = __builtin_amdgcn_cvt_pk_bf16_f32(a, b);
    return __builtin_bit_cast(u32, r);
#else
    u32 ua = __builtin_bit_cast(u32, a), ub = __builtin_bit_cast(u32, b);
    return (ua >> 16) | (ub & 0xffff0000u);
#endif
}
__device__ __forceinline__ float frcp(float x) {
#ifdef HAVE_RCPF
    return __builtin_amdgcn_rcpf(x);
#else
    return 1.0f / x;
#endif
}
__device__ __forceinline__ void gload_lds16(const u16* g, u16* l) {
    __builtin_amdgcn_global_load_lds((__attribute__((address_space(1))) void*)(u16*)g,
                                     (__attribute__((address_space(3))) void*)l, 16, 0, 0);
}
// tanh-GELU in sigmoid form (|err| < 1e-3, below bf16 rounding of the result)
__device__ __forceinline__ float gelu_f(float v) {
    float y2 = v * (1.5957691216f + 0.0713548576f * v * v);
    return v / (1.0f + __expf(-y2));
}

// ---------------------------------------------------------------- PE table (b,e) -> 2048 floats
__global__ __launch_bounds__(256) void pe_tab_k(float* __restrict__ pet) {
    int i = blockIdx.x * 256 + threadIdx.x;          // 2048
    int e = i & (E_DIM - 1);
    float t = (float)(i >> 9) + 1.0f;
    int ee = (e & 1) ? (e + 1) : e;
    float w = exp2f((-(float)ee / 512.0f) * 13.287712379549449f);
    pet[i] = (e & 1) ? cosf(t * w) : sinf(t * w);
}

// ---------------------------------------------------------------- fused x+pe->bf16 (blocks 0..4095) and
// fp32->bf16 weight conversion (blocks 4096..7167)
__global__ __launch_bounds__(256) void prep_k(const float* __restrict__ x,
                                              const float* __restrict__ pet,
                                              u16* __restrict__ xpb,
                                              const float* __restrict__ s1, u16* __restrict__ d1, int n1,
                                              const float* __restrict__ s2, u16* __restrict__ d2, int n2,
                                              const float* __restrict__ s3, u16* __restrict__ d3, int n3,
                                              const float* __restrict__ s4, u16* __restrict__ d4) {
    int bid = blockIdx.x;
    if (bid < 4096) {
        int idx = (bid * 256 + threadIdx.x) * 4;
        f4v v = *(const f4v*)(x + idx);
        f4v p = *(const f4v*)(pet + (idx & 2047));
        u16x4 o;
#pragma unroll
        for (int i = 0; i < 4; ++i) o[i] = f2b(v[i] + p[i]);
        *(u16x4*)(xpb + idx) = o;
    } else {
        int o = ((bid - 4096) * 256 + threadIdx.x) * 4;
        const float* s; u16* d;
        if (o < n1) { s = s1; d = d1; }
        else { o -= n1;
            if (o < n2) { s = s2; d = d2; }
            else { o -= n2;
                if (o < n3) { s = s3; d = d3; }
                else { o -= n3; s = s4; d = d4; } } }
        f4v v = *(const f4v*)(s + o);
        u16x4 q;
#pragma unroll
        for (int i = 0; i < 4; ++i) q[i] = f2b(v[i]);
        *(u16x4*)(d + o) = q;
    }
}

// ---------------------------------------------------------------- LN combine (wave per row)
template <int NP, bool WRITEF, bool WRITEB>
__global__ __launch_bounds__(256)
void ln_c(const u16* __restrict__ p0, const u16* __restrict__ p1,
          const u16* __restrict__ p2, const u16* __restrict__ p3,
          const float* __restrict__ bias, const u16* __restrict__ resid,
          const float* __restrict__ gw, const float* __restrict__ bw,
          float* __restrict__ outF, u16* __restrict__ outB) {
    int wave = threadIdx.x >> 6, lane = threadIdx.x & 63;
    size_t row = (size_t)blockIdx.x * 4 + wave;
    size_t off = row * E_DIM + lane * 8;
    u16x8 rv = *(const u16x8*)(resid + off);
    f4v a, b;
#pragma unroll
    for (int i = 0; i < 4; ++i) { a[i] = b2f(rv[i]); b[i] = b2f(rv[i + 4]); }
    a += *(const f4v*)(bias + lane * 8);
    b += *(const f4v*)(bias + lane * 8 + 4);
    const u16* ps[4] = {p0, p1, p2, p3};
#pragma unroll
    for (int z = 0; z < NP; ++z) {
        u16x8 t = *(const u16x8*)(ps[z] + off);
#pragma unroll
        for (int i = 0; i < 4; ++i) { a[i] += b2f(t[i]); b[i] += b2f(t[i + 4]); }
    }
    float s = (a[0] + a[1]) + (a[2] + a[3]) + (b[0] + b[1]) + (b[2] + b[3]);
#pragma unroll
    for (int o = 1; o < 64; o <<= 1) s += __shfl_xor(s, o, 64);
    float mu = s * (1.0f / E_DIM);
    float q = 0.f;
#pragma unroll
    for (int i = 0; i < 4; ++i) { float d = a[i] - mu; q += d * d; }
#pragma unroll
    for (int i = 0; i < 4; ++i) { float d = b[i] - mu; q += d * d; }
#pragma unroll
    for (int o = 1; o < 64; o <<= 1) q += __shfl_xor(q, o, 64);
    float rstd = rsqrtf(q * (1.0f / E_DIM) + 1e-5f);
    f4v g0 = *(const f4v*)(gw + lane * 8), g1 = *(const f4v*)(gw + lane * 8 + 4);
    f4v w0 = *(const f4v*)(bw + lane * 8), w1 = *(const f4v*)(bw + lane * 8 + 4);
    f4v y0, y1;
#pragma unroll
    for (int i = 0; i < 4; ++i) { y0[i] = (a[i] - mu) * rstd * g0[i] + w0[i];
                                  y1[i] = (b[i] - mu) * rstd * g1[i] + w1[i]; }
    if (WRITEF) {
        *(f4v*)(outF + off)     = y0;
        *(f4v*)(outF + off + 4) = y1;
    }
    if (WRITEB) {
        u16x8 o;
#pragma unroll
        for (int i = 0; i < 4; ++i) { o[i] = f2b(y0[i]); o[i + 4] = f2b(y1[i]); }
        *(u16x8*)(outB + off) = o;
    }
}

// ---------------------------------------------------------------- K-split partial GEMM BK32 dbuf + XCD swizzle (R14)
__global__ __launch_bounds__(256, 4)
void gemm_ks(const u16* __restrict__ A, const u16* __restrict__ Bw,
             int N, int K, int Kper,
             u16* __restrict__ q0, u16* __restrict__ q1) {
    __shared__ __align__(16) u16 As[2][128 * 32];
    __shared__ __align__(16) u16 Bs[2][128 * 32];
    const int tid = threadIdx.x;
    const int wave = tid >> 6, lane = tid & 63;
    const int col = lane & 15, quad = lane >> 4;
    const int n = blockIdx.x;
    const int xcd = n & 7, loc = n >> 3;             // loc in [0,64)
    const int bn = (loc & 3) * 128;
    const int bm = (xcd * 8 + ((loc >> 2) & 7)) * 128;
    const int kz = loc >> 5;
    u16* pz = kz ? q1 : q0;
    const int wm = (wave >> 1) * 64, wn = (wave & 1) * 64;
    f4v acc[4][4] = {};
    const int srow = wave * 16 + (lane >> 2);
    const int soff = (lane & 3) * 8;
    const u16* Ag = A + (size_t)(bm + srow) * K + kz * Kper + soff;
    const u16* Bg = Bw + (size_t)(bn + srow) * K + kz * Kper + soff;
    const int wo = wave * 512;
    gload_lds16(Ag,                  &As[0][wo]);
    gload_lds16(Ag + (size_t)64 * K, &As[0][wo + 2048]);
    gload_lds16(Bg,                  &Bs[0][wo]);
    gload_lds16(Bg + (size_t)64 * K, &Bs[0][wo + 2048]);
    const int nit = Kper >> 5;
    for (int t = 0; t < nit; ++t) {
        const int cur = t & 1, nxt = cur ^ 1;
        __syncthreads();
        if (t + 1 < nit) {
            const int kc = (t + 1) * 32;
            gload_lds16(Ag + kc,                  &As[nxt][wo]);
            gload_lds16(Ag + (size_t)64 * K + kc, &As[nxt][wo + 2048]);
            gload_lds16(Bg + kc,                  &Bs[nxt][wo]);
            gload_lds16(Bg + (size_t)64 * K + kc, &Bs[nxt][wo + 2048]);
        }
        s8v af[4], bf[4];
#pragma unroll
        for (int i = 0; i < 4; ++i) af[i] = *(const s8v*)(&As[cur][(wm + i * 16 + col) * 32 + quad * 8]);
#pragma unroll
        for (int j = 0; j < 4; ++j) bf[j] = *(const s8v*)(&Bs[cur][(wn + j * 16 + col) * 32 + quad * 8]);
#pragma unroll
        for (int i = 0; i < 4; ++i)
#pragma unroll
            for (int j = 0; j < 4; ++j)
                acc[i][j] = __builtin_amdgcn_mfma_f32_16x16x32_bf16(af[i], bf[j], acc[i][j], 0, 0, 0);
    }
#pragma unroll
    for (int j = 0; j < 4; ++j) {
        int gn = bn + wn + j * 16 + col;
#pragma unroll
        for (int i = 0; i < 4; ++i) {
            int m0 = bm + wm + i * 16 + quad * 4;
#pragma unroll
            for (int r = 0; r < 4; ++r)
                pz[(size_t)(m0 + r) * N + gn] = f2b(acc[i][j][r]);
        }
    }
}

// ---------------------------------------------------------------- GEMM 256x128 BK32, 8 waves (4x2), 3-deep ring,
// counted vmcnt, chunk XOR swizzle, setprio. KTILES k-tiles per block, KZL-way K-split.
// MODE 0: QKV scatter (Q pre-scaled; V-blocks (nt>=8) do an in-LDS transpose and write V^T directly).
// MODE 2: bias+GELU->bf16. MODE 3: raw bf16 partial to o[kz].
#define G28_STAGE(Ad, Bd, kf)                                                          \
    {                                                                                  \
        _Pragma("unroll")                                                              \
        for (int s = 0; s < 2; ++s) {                                                  \
            const int qa = s * 512 + tid;                                              \
            const int rhoA = qa >> 2;                                                  \
            gload_lds16(A + (size_t)(bm + rhoA) * Ka + koff + (kf) + gsw, (Ad) + qa * 8); \
        }                                                                              \
        {                                                                              \
            const int rhoB = tid >> 2;                                                 \
            gload_lds16(Bw + (size_t)(bn + rhoB) * Kb + koff + (kf) + gsw, (Bd) + tid * 8); \
        }                                                                              \
    }

#define G28_COMPUTE(Ab_, Bb_)                                                          \
    {                                                                                  \
        s8v bfr[4], afr[4];                                                            \
        _Pragma("unroll")                                                              \
        for (int j = 0; j < 4; ++j) {                                                  \
            const int rB = wc * 64 + j * 16 + col;                                     \
            bfr[j] = *(const s8v*)((Bb_) + rB * 32 + ((quad ^ ((rB >> 1) & 3)) * 8));  \
        }                                                                              \
        _Pragma("unroll")                                                              \
        for (int i = 0; i < 4; ++i) {                                                  \
            const int rA = wr * 64 + i * 16 + col;                                     \
            afr[i] = *(const s8v*)((Ab_) + rA * 32 + ((quad ^ ((rA >> 1) & 3)) * 8));  \
        }                                                                              \
        __builtin_amdgcn_s_setprio(1);                                                 \
        _Pragma("unroll")                                                              \
        for (int i = 0; i < 4; ++i)                                                    \
            _Pragma("unroll")                                                          \
            for (int j = 0; j < 4; ++j)                                                \
                acc[i][j] = __builtin_amdgcn_mfma_f32_16x16x32_bf16(afr[i], bfr[j], acc[i][j], 0, 0, 0); \
        __builtin_amdgcn_s_setprio(0);                                                 \
    }

template <int MODE, int NTL, int KZL, int KTILES>
__global__ __launch_bounds__(512, 2)
void g28(const u16* __restrict__ A, const u16* __restrict__ Bw,
         const float* __restrict__ bias, int Ka, int Kb, int N,
         u16* __restrict__ o0, u16* __restrict__ o1, u16* __restrict__ o2) {
    extern __shared__ __align__(16) u16 LDS[];       // 3 x (A 8192 + B 4096) u16 = 72 KB
    const int tid = threadIdx.x;
    const int wave = tid >> 6, lane = tid & 63;
    const int col = lane & 15, quad = lane >> 4;
    const int wr = wave >> 1, wc = wave & 1;
    const int n = blockIdx.x;
    const int xcd = n & 7, loc = n >> 3;             // loc in [0, 4*NTL*KZL)
    const int mt = xcd * 4 + (loc & 3);
    const int rest = loc >> 2;
    const int nt = (NTL == 1) ? 0 : (rest % NTL);
    const int kz = (KZL == 1) ? 0 : (rest / NTL);
    const int bm = mt * 256, bn = nt * 128;
    const int koff = kz * (KTILES * 32);
    const int gsw = ((lane & 3) ^ ((lane >> 3) & 3)) * 8;
    f4v acc[4][4] = {};
    u16* A0 = LDS;          u16* B0 = LDS + 8192;
    u16* A1 = LDS + 12288;  u16* B1 = LDS + 20480;
    u16* A2 = LDS + 24576;  u16* B2 = LDS + 32768;
    G28_STAGE(A0, B0, 0);
    G28_STAGE(A1, B1, 32);
    asm volatile("s_waitcnt vmcnt(3)" ::: "memory");
    __builtin_amdgcn_s_barrier();
    __builtin_amdgcn_sched_barrier(0);
    for (int t = 0; t < KTILES - 2; ++t) {
        G28_STAGE(A2, B2, (t + 2) * 32);
        G28_COMPUTE(A0, B0);
        asm volatile("s_waitcnt vmcnt(3)" ::: "memory");
        __builtin_amdgcn_s_barrier();
        __builtin_amdgcn_sched_barrier(0);
        u16* ta = A0; A0 = A1; A1 = A2; A2 = ta;
        u16* tb = B0; B0 = B1; B1 = B2; B2 = tb;
    }
    G28_COMPUTE(A0, B0);                              // tile KTILES-2
    asm volatile("s_waitcnt vmcnt(0)" ::: "memory");
    __builtin_amdgcn_s_barrier();
    __builtin_amdgcn_sched_barrier(0);
    G28_COMPUTE(A1, B1);                              // tile KTILES-1
    if (MODE == 0 && nt >= 8) {
        // V-block: in-LDS transpose, write V^T [b][h][d][l] directly (o2 = VT).
        __syncthreads();                              // all ring reads done; reuse LDS
        u16* xb = LDS;                                // [128 ln][256 lm] stride 264 (bank-safe)
#pragma unroll
        for (int j = 0; j < 4; ++j) {
            const int ln = wc * 64 + j * 16 + col;
            const float bv = bias[nt * 128 + ln];
#pragma unroll
            for (int i = 0; i < 4; ++i) {
                const int lm = wr * 64 + i * 16 + quad * 4;
#pragma unroll
                for (int r = 0; r < 4; ++r)
                    xb[ln * 264 + lm + r] = f2b(acc[i][j][r] + bv);
            }
        }
        __syncthreads();
        const int l0 = bm >> 2;
        for (int rr = 0; rr < 64; ++rr) {
            const int rid = wave * 64 + rr;
            const int ln = rid >> 2, b = rid & 3;
            const int h = (nt - 8) * 2 + (ln >> 6), d = ln & 63;
            u16 v = xb[ln * 264 + lane * 4 + b];
            o2[((size_t)(b * H_CNT + h) * HD + d) * L_SEQ + l0 + lane] = v;
        }
        return;
    }
#pragma unroll
    for (int j = 0; j < 4; ++j) {
        const int gn = bn + wc * 64 + j * 16 + col;
        if (MODE == 0) {
            const float bv = bias[gn];
            const int which = gn >> 9, hh = (gn >> 6) & 7, d = gn & 63;
            u16* dst = (which == 0) ? o0 : o1;
            const float qs = (which == 0) ? QSCALE : 1.0f;
#pragma unroll
            for (int i = 0; i < 4; ++i) {
                const int m0 = bm + wr * 64 + i * 16 + quad * 4;
#pragma unroll
                for (int r = 0; r < 4; ++r) {
                    const int m = m0 + r;
                    const int l = m >> 2, bb = m & 3;
                    dst[((size_t)(bb * H_CNT + hh) * L_SEQ + l) * HD + d] = f2b((acc[i][j][r] + bv) * qs);
                }
            }
        } else if (MODE == 2) {
            const float bv = bias[gn];
#pragma unroll
            for (int i = 0; i < 4; ++i) {
                const int m0 = bm + wr * 64 + i * 16 + quad * 4;
#pragma unroll
                for (int r = 0; r < 4; ++r)
                    o0[(size_t)(m0 + r) * N + gn] = f2b(gelu_f(acc[i][j][r] + bv));
            }
        } else {
            u16* pz = (kz == 0) ? o0 : o1;
#pragma unroll
            for (int i = 0; i < 4; ++i) {
                const int m0 = bm + wr * 64 + i * 16 + quad * 4;
#pragma unroll
                for (int r = 0; r < 4; ++r)
                    pz[(size_t)(m0 + r) * N + gn] = f2b(acc[i][j][r]);
            }
        }
    }
}

// ---------------------------------------------------------------- flash attention v13 (proven R8):
// 8-wave blocks = 2 kv-groups x 4 waves; group 1 dumps fp32 partials into its dead K/V LDS; group 0 combines.
__global__ __launch_bounds__(512, 4)
void attn_k(const u16* __restrict__ qg, const u16* __restrict__ kg,
            const u16* __restrict__ vtg, u16* __restrict__ og) {
    __shared__ __align__(16) u16 KV[2][2][2][2][64 * 32];   // [group][K/V][dbuf][h][.] = 64 KB
    __shared__ float LSB[2][256];                           // l partials, 2 KB
    const int tid = threadIdx.x;
    const int wave = tid >> 6, lane = tid & 63;
    const int grp = wave >> 2, w4 = wave & 3;
    const int col = lane & 15, quad = lane >> 4;
    const int flat = blockIdx.x;
    const int xcd = flat & 7, loc = flat >> 3;       // loc in [0,64)
    const int bh = xcd * 4 + (loc >> 4);             // 4 heads per XCD
    const int qc = loc & 15;
    const size_t base = (size_t)bh * (L_SEQ * HD);
    s8v qf[2][2];
#pragma unroll
    for (int t = 0; t < 2; ++t) {
        const int qrow = qc * 128 + w4 * 32 + t * 16 + col;
#pragma unroll
        for (int hh = 0; hh < 2; ++hh)
            qf[t][hh] = *(const s8v*)(qg + base + (size_t)qrow * HD + hh * 32 + quad * 8);
    }
    f4v oa[2][4] = {};
    float ls0 = 0.f, ls1 = 0.f;
    const int h = w4 & 1, r0 = (w4 >> 1) * 16;
    const int srow = lane >> 2, c = lane & 3;
    const int cp = c ^ ((srow >> 1) & 3);            // XOR-swizzled 16B chunk fetch
    // sigma row permutation: LDS row rho holds K-row 32*(rho>>5)+8*((rho>>2)&3)+4*((rho>>4)&1)+(rho&3)
    const int sig = ((srow >> 2) << 3) + ((r0 >> 4) << 2) + (srow & 3);
    const u16* Kg = kg + base + (size_t)(sig + grp * 1024) * HD + h * 32 + cp * 8;
    const u16* Vg = vtg + base + (size_t)(r0 + srow) * L_SEQ + grp * 1024 + h * 32 + cp * 8;
    {
        gload_lds16(Kg,                      &KV[grp][0][0][h][r0 * 32]);
        gload_lds16(Kg + (size_t)32 * HD,    &KV[grp][0][0][h][(r0 + 32) * 32]);
        gload_lds16(Vg,                      &KV[grp][1][0][h][r0 * 32]);
        gload_lds16(Vg + (size_t)32 * L_SEQ, &KV[grp][1][0][h][(r0 + 32) * 32]);
    }
    const int perm = (col >> 1) & 3;
    for (int it = 0; it < 16; ++it) {
        const int cur = it & 1, nxt = cur ^ 1;
        __syncthreads();
        if (it + 1 < 16) {
            const int kv0 = (it + 1) * 64;
            gload_lds16(Kg + (size_t)kv0 * HD,         &KV[grp][0][nxt][h][r0 * 32]);
            gload_lds16(Kg + (size_t)(kv0 + 32) * HD,  &KV[grp][0][nxt][h][(r0 + 32) * 32]);
            gload_lds16(Vg + kv0,                      &KV[grp][1][nxt][h][r0 * 32]);
            gload_lds16(Vg + kv0 + (size_t)32 * L_SEQ, &KV[grp][1][nxt][h][(r0 + 32) * 32]);
        }
        f4v st[2][4];
#pragma unroll
        for (int j = 0; j < 4; ++j) {
            s8v k0 = *(const s8v*)(&KV[grp][0][cur][0][(j * 16 + col) * 32 + ((quad ^ perm) * 8)]);
            s8v k1 = *(const s8v*)(&KV[grp][0][cur][1][(j * 16 + col) * 32 + ((quad ^ perm) * 8)]);
#pragma unroll
            for (int t = 0; t < 2; ++t) {
                f4v z = {};
                z = __builtin_amdgcn_mfma_f32_16x16x32_bf16(k0, qf[t][0], z, 0, 0, 0);
                z = __builtin_amdgcn_mfma_f32_16x16x32_bf16(k1, qf[t][1], z, 0, 0, 0);
                st[t][j] = z;
            }
        }
        u32 pk[2][4][2];
#pragma unroll
        for (int t = 0; t < 2; ++t)
#pragma unroll
            for (int j = 0; j < 4; ++j) {
                f4v p;
#pragma unroll
                for (int r = 0; r < 4; ++r) p[r] = __builtin_amdgcn_exp2f(st[t][j][r]);
                float psum = (p[0] + p[1]) + (p[2] + p[3]);
                if (t == 0) ls0 += psum; else ls1 += psum;
                pk[t][j][0] = pk_trunc(p[0], p[1]);
                pk[t][j][1] = pk_trunc(p[2], p[3]);
            }
#pragma unroll
        for (int c2 = 0; c2 < 2; ++c2) {
            s8v pf[2];
#pragma unroll
            for (int t = 0; t < 2; ++t) {
                u32x4 q4 = {pk[t][2 * c2][0], pk[t][2 * c2][1],
                            pk[t][2 * c2 + 1][0], pk[t][2 * c2 + 1][1]};
                pf[t] = __builtin_bit_cast(s8v, q4);
            }
#pragma unroll
            for (int dj = 0; dj < 4; ++dj) {
                s8v vf = *(const s8v*)(&KV[grp][1][cur][c2][(dj * 16 + col) * 32 + ((quad ^ perm) * 8)]);
#pragma unroll
                for (int t = 0; t < 2; ++t)
                    oa[t][dj] = __builtin_amdgcn_mfma_f32_16x16x32_bf16(pf[t], vf, oa[t][dj], 0, 0, 0);
            }
        }
    }
    // reduce l over quads within each group (lanes sharing col)
    ls0 += __shfl_xor(ls0, 16, 64); ls0 += __shfl_xor(ls0, 32, 64);
    ls1 += __shfl_xor(ls1, 16, 64); ls1 += __shfl_xor(ls1, 32, 64);
    // cross-group combine via group-1's (dead) K/V LDS region (exactly 32 KB)
    float* cmb = (float*)&KV[1][0][0][0][0];
    const int slot = w4 * 64 + lane;
    if (grp == 1) {
#pragma unroll
        for (int t = 0; t < 2; ++t)
#pragma unroll
            for (int dj = 0; dj < 4; ++dj)
                *(f4v*)(cmb + ((size_t)(t * 4 + dj) * 256 + slot) * 4) = oa[t][dj];
        LSB[0][slot] = ls0;
        LSB[1][slot] = ls1;
    }
    __syncthreads();
    if (grp == 0) {
#pragma unroll
        for (int t = 0; t < 2; ++t)
#pragma unroll
            for (int dj = 0; dj < 4; ++dj)
                oa[t][dj] += *(const f4v*)(cmb + ((size_t)(t * 4 + dj) * 256 + slot) * 4);
        ls0 += LSB[0][slot];
        ls1 += LSB[1][slot];
        const int b = bh >> 3, hd = bh & 7;
#pragma unroll
        for (int t = 0; t < 2; ++t)
#pragma unroll
            for (int r = 0; r < 4; ++r) {
                float lv = __shfl(t == 0 ? ls0 : ls1, quad * 4 + r, 64);
                float inv = frcp(lv);
                int lrow = qc * 128 + w4 * 32 + t * 16 + quad * 4 + r;
                size_t mrow = (size_t)(lrow * 4 + b) * E_DIM + hd * HD;
#pragma unroll
                for (int dj = 0; dj < 4; ++dj)
                    og[mrow + dj * 16 + col] = f2b(oa[t][dj][r] * inv);
            }
    }
}

// ---------------------------------------------------------------- host
extern "C" void kernel_launch(void* const* d_in, const int* in_sizes, int n_in,
                              void* d_out, int out_size, void* d_ws, size_t ws_size,
                              hipStream_t stream) {
    const float* x     = (const float*)d_in[0];
    const float* w_qkv = (const float*)d_in[1];
    const float* b_qkv = (const float*)d_in[2];
    const float* w_out = (const float*)d_in[3];
    const float* b_out = (const float*)d_in[4];
    const float* w1    = (const float*)d_in[5];
    const float* b1    = (const float*)d_in[6];
    const float* w2    = (const float*)d_in[7];
    const float* b2    = (const float*)d_in[8];
    const float* ln_g  = (const float*)d_in[9];
    const float* ln_b  = (const float*)d_in[10];

    char* ws = (char*)d_ws;
    u16*   WQKV = (u16*)(ws + 0);                    // 1.5 MB
    u16*   WOUT = (u16*)(ws + 1572864);              // 0.5 MB
    u16*   W1B  = (u16*)(ws + 2097152);              // 2 MB
    u16*   W2B  = (u16*)(ws + 4194304);              // 2 MB
    u16*   XPB  = (u16*)(ws + 6291456);              // 8 MB  x+pe bf16 (resid 1)
    u16*   QB   = (u16*)(ws + 14680064);             // 8 MB
    u16*   KB   = (u16*)(ws + 23068672);             // 8 MB
    u16*   VB   = (u16*)(ws + 31457280);             // 8 MB (attn out; V^T written directly to VT)
    u16*   VT   = (u16*)(ws + 39845888);             // 8 MB
    float* PET  = (float*)(ws + 82837504);           // 8 KB PE table
    // aliases (disjoint lifetimes):
    u16*   OB   = VB;                                // attn out
    u16*   OP0  = (u16*)(ws + 48234496);             // out-proj partials
    u16*   OP1  = (u16*)(ws + 56623104);
    u16*   X3B  = QB;                                // LN1 out bf16 (QB free after attn; resid 2)
    u16*   HB   = (u16*)(ws + 48234496);             // FFN1 out 32MB (over OPx, free after ln_c)
    u16*   FP0  = XPB;                               // FFN2 partials (free by FFN2)
    u16*   FP1  = KB;

    static bool attr_done = false;
    if (!attr_done) {
        hipFuncSetAttribute((const void*)g28<0, 12, 1, 16>,
                            hipFuncAttributeMaxDynamicSharedMemorySize, 73728);
        hipFuncSetAttribute((const void*)g28<2, 16, 1, 16>,
                            hipFuncAttributeMaxDynamicSharedMemorySize, 73728);
        hipFuncSetAttribute((const void*)g28<3, 4, 2, 32>,
                            hipFuncAttributeMaxDynamicSharedMemorySize, 73728);
        attr_done = true;
    }

    pe_tab_k<<<8, 256, 0, stream>>>(PET);
    prep_k<<<7168, 256, 0, stream>>>(x, PET, XPB,
                                     w_qkv, WQKV, 3 * E_DIM * E_DIM,
                                     w_out, WOUT, E_DIM * E_DIM,
                                     w1, W1B, HID * E_DIM,
                                     w2, W2B);
    g28<0, 12, 1, 16><<<384, 512, 73728, stream>>>(XPB, WQKV, b_qkv, E_DIM, E_DIM, 0,
                                                   QB, KB, VT);
    attn_k<<<512, 512, 0, stream>>>(QB, KB, VT, OB);
    gemm_ks<<<512, 256, 0, stream>>>(OB, WOUT, E_DIM, E_DIM, 256, OP0, OP1);
    ln_c<2, false, true><<<2048, 256, 0, stream>>>(OP0, OP1, nullptr, nullptr,
                                                   b_out, XPB, ln_g, ln_b, nullptr, X3B);
    g28<2, 16, 1, 16><<<512, 512, 73728, stream>>>(X3B, W1B, b1, E_DIM, E_DIM, HID,
                                                   HB, nullptr, nullptr);
    g28<3, 4, 2, 32><<<256, 512, 73728, stream>>>(HB, W2B, nullptr, HID, HID, E_DIM,
                                                  FP0, FP1, nullptr);
    ln_c<2, true, false><<<2048, 256, 0, stream>>>(FP0, FP1, nullptr, nullptr,
                                                   b2, X3B, ln_g, ln_b, (float*)d_out, nullptr);
}